// Round 2
// baseline (2014.330 us; speedup 1.0000x reference)
//
#include <hip/hip_runtime.h>
#include <hip/hip_bf16.h>

typedef __hip_bfloat16 bf16;
typedef short s8v __attribute__((ext_vector_type(8)));   // 8 bf16 in 4 VGPRs
typedef float f4v __attribute__((ext_vector_type(4)));   // MFMA 16x16 C/D frag

__device__ __forceinline__ short f2b(float f) {
  bf16 h = __float2bfloat16(f);
  return *reinterpret_cast<short*>(&h);
}
__device__ __forceinline__ float bf_lo(int x) { return __int_as_float(x << 16); }
__device__ __forceinline__ float bf_hi(int x) { return __int_as_float(x & 0xFFFF0000); }

#define BSHIFT 6         // 64 dest nodes per bucket -> all agg blocks co-resident
#define BNODES 64
#define TSHIFT 14        // source tile = 16K rows = 2 MB of g1 (fits per-XCD L2)
#define TILES 8
#define CHUNK 4096       // edges per chunk
#define SORT_CAP 4096    // bucket LDS capacity; mean bucket = 2048 (45 sigma margin)
#define NBUCK_MAX 1600   // >= ceil(100000/64)=1563

// ---- phase 1: per-chunk bucket histogram (LDS atomics only) ----
__global__ __launch_bounds__(256) void k_hist(const int* __restrict__ col, int E,
                                              int nbuck, int* __restrict__ chist) {
  __shared__ int hist[NBUCK_MAX];
  int t = threadIdx.x;
  for (int b = t; b < nbuck; b += 256) hist[b] = 0;
  __syncthreads();
  int e0 = blockIdx.x * CHUNK;
#pragma unroll
  for (int i = 0; i < 16; i++) {
    int e = e0 + i * 256 + t;
    if (e < E) atomicAdd(&hist[col[e] >> BSHIFT], 1);
  }
  __syncthreads();
  int* out = chist + (size_t)blockIdx.x * nbuck;
  for (int b = t; b < nbuck; b += 256) out[b] = hist[b];  // coalesced
}

// ---- phase 2: per-bucket exclusive scan over chunks (in place) ----
__global__ __launch_bounds__(256) void k_scanbuck(int* __restrict__ chist, int nchnk,
                                                  int nbuck, int* __restrict__ btot) {
  __shared__ int sm[256];
  int b = blockIdx.x, t = threadIdx.x;
  int per = (nchnk + 255) / 256;
  int lo = t * per, hi = min(lo + per, nchnk);
  int s = 0;
  for (int i = lo; i < hi; i++) s += chist[(size_t)i * nbuck + b];
  sm[t] = s;
  __syncthreads();
  for (int d = 1; d < 256; d <<= 1) {
    int x = (t >= d) ? sm[t - d] : 0;
    __syncthreads();
    sm[t] += x;
    __syncthreads();
  }
  int off = (t == 0) ? 0 : sm[t - 1];
  for (int i = lo; i < hi; i++) {
    int c = chist[(size_t)i * nbuck + b];
    chist[(size_t)i * nbuck + b] = off;
    off += c;
  }
  if (t == 255) btot[b] = sm[255];
}

// ---- phase 3: scan bucket totals (512 thr x 4 contiguous, nbuck <= 2048) ----
__global__ __launch_bounds__(512) void k_scanbase(const int* __restrict__ btot, int nbuck,
                                                  int* __restrict__ bbase) {
  __shared__ int sm[512];
  int t = threadIdx.x;
  int b0 = 4 * t;
  int v0 = (b0     < nbuck) ? btot[b0]     : 0;
  int v1 = (b0 + 1 < nbuck) ? btot[b0 + 1] : 0;
  int v2 = (b0 + 2 < nbuck) ? btot[b0 + 2] : 0;
  int v3 = (b0 + 3 < nbuck) ? btot[b0 + 3] : 0;
  int s = v0 + v1 + v2 + v3;
  sm[t] = s;
  __syncthreads();
  for (int d = 1; d < 512; d <<= 1) {   // Hillis-Steele inclusive
    int x = (t >= d) ? sm[t - d] : 0;
    __syncthreads();
    sm[t] += x;
    __syncthreads();
  }
  int off = sm[t] - s;                  // exclusive prefix
  if (b0     < nbuck) bbase[b0]     = off;
  if (b0 + 1 < nbuck) bbase[b0 + 1] = off + v0;
  if (b0 + 2 < nbuck) bbase[b0 + 2] = off + v0 + v1;
  if (b0 + 3 < nbuck) bbase[b0 + 3] = off + v0 + v1 + v2;
  if (t == 511) bbase[nbuck] = sm[511];   // == E
}

// ---- phase 4: grouped scatter into bucket-grouped adj, NO global atomics ----
// adj entry: r | (c_low << 17)   (c_low = 6 bits, kept for the LDS-accum agg)
__global__ __launch_bounds__(256) void k_binpass(const int* __restrict__ row,
                                                 const int* __restrict__ col, int E,
                                                 int nbuck,
                                                 const int* __restrict__ bbase,
                                                 const int* __restrict__ chist,
                                                 int* __restrict__ adj) {
  __shared__ int hist[NBUCK_MAX];
  __shared__ int base[NBUCK_MAX];
  __shared__ int lcur[NBUCK_MAX];
  __shared__ int gbase[NBUCK_MAX];
  __shared__ int psum[256];
  __shared__ int stage[CHUNK];
  __shared__ unsigned short sbkt[CHUNK];
  __shared__ int s_total;
  int t = threadIdx.x;
  int e0 = blockIdx.x * CHUNK;

  for (int b = t; b < nbuck; b += 256) hist[b] = 0;
  __syncthreads();

  int pk[16], bk[16];
#pragma unroll
  for (int i = 0; i < 16; i++) {
    int e = e0 + i * 256 + t;
    if (e < E) {
      int c = col[e];
      int r = row[e];
      bk[i] = c >> BSHIFT;
      pk[i] = r | ((c & (BNODES - 1)) << 17);
      atomicAdd(&hist[bk[i]], 1);
    } else bk[i] = -1;
  }
  __syncthreads();
  int PB = (nbuck + 255) >> 8;          // buckets per thread (=7)
  int b0 = t * PB;
  int s = 0;
  for (int i = 0; i < PB; i++) { int b = b0 + i; if (b < nbuck) s += hist[b]; }
  psum[t] = s;
  __syncthreads();
  for (int d = 1; d < 256; d <<= 1) {
    int v = (t >= d) ? psum[t - d] : 0;
    __syncthreads();
    psum[t] += v;
    __syncthreads();
  }
  int off = psum[t] - s;
  for (int i = 0; i < PB; i++) {
    int b = b0 + i;
    if (b < nbuck) { base[b] = off; lcur[b] = off; off += hist[b]; }
  }
  if (t == 255) s_total = psum[255];
  const int* coff = chist + (size_t)blockIdx.x * nbuck;
  for (int b = t; b < nbuck; b += 256) gbase[b] = bbase[b] + coff[b];
  __syncthreads();
#pragma unroll
  for (int i = 0; i < 16; i++) {
    if (bk[i] >= 0) {
      int pos = atomicAdd(&lcur[bk[i]], 1);
      stage[pos] = pk[i];
      sbkt[pos] = (unsigned short)bk[i];
    }
  }
  __syncthreads();
  int total = s_total;
  for (int i = t; i < total; i += 256) {
    int b = sbkt[i];
    adj[gbase[b] + (i - base[b])] = stage[i];
  }
}

// ---- phase 5: per-bucket TILE sort (8 keys), in place; emits dinv ----
// Dest order inside a tile stays random on purpose: the LDS-accum aggregate
// relies on random c_low to avoid same-address ds_add serialization.
__global__ __launch_bounds__(256) void k_bucketsort(const int* __restrict__ bbase,
                                                    int* __restrict__ adj,
                                                    float* __restrict__ dinv, int n) {
  __shared__ int cnt[TILES];
  __shared__ int cur[TILES];
  __shared__ int deg[BNODES];
  __shared__ int stage[SORT_CAP];
  int b = blockIdx.x, t = threadIdx.x;
  int node_base = b << BSHIFT;
  int seg = bbase[b];
  int cntE = bbase[b + 1] - seg;
  if (t < TILES) cnt[t] = 0;
  if (t < BNODES) deg[t] = 0;
  __syncthreads();
  for (int i = t; i < cntE; i += 256) {
    int p = adj[seg + i];
    atomicAdd(&cnt[(p & 0x1FFFF) >> TSHIFT], 1);
    atomicAdd(&deg[p >> 17], 1);
  }
  __syncthreads();
  if (t == 0) {
    int off = 0;
#pragma unroll
    for (int m = 0; m < TILES; m++) { cur[m] = off; off += cnt[m]; }
  }
  if (t < BNODES) {
    int node = node_base + t;
    if (node < n) dinv[node] = rsqrtf((float)deg[t] + 1.0f);  // +1 = self-loop
  }
  __syncthreads();
  if (cntE <= SORT_CAP) {
    for (int i = t; i < cntE; i += 256) {
      int p = adj[seg + i];
      int pos = atomicAdd(&cur[(p & 0x1FFFF) >> TSHIFT], 1);
      stage[pos] = p;
    }
    __syncthreads();   // all reads done before in-place writeback
    for (int i = t; i < cntE; i += 256) adj[seg + i] = stage[i];
  }
  // else: leave bucket unsorted (correct, only loses tile locality) — never hit
}

// ---- weight prep: Wt1[64][128] = W1^T bf16, Wt2[32][64] = W2^T bf16 ----
__global__ __launch_bounds__(256) void k_prepW(const float* __restrict__ W1,
                                               const float* __restrict__ W2,
                                               short* __restrict__ Wt1,
                                               short* __restrict__ Wt2) {
  int t = blockIdx.x * 256 + threadIdx.x;
  if (t < 128 * 64) { int k = t >> 6, c = t & 63; Wt1[c * 128 + k] = f2b(W1[t]); }
  if (t < 64 * 32)  { int k = t >> 5, c = t & 31; Wt2[c * 64 + k] = f2b(W2[t]); }
}

// ---- MFMA gemm1: g1[n,64] = dinv[r]*(x[n,128] @ W1[128,64]), bf16 out ----
__global__ __launch_bounds__(256) void k_gemm1(const float* __restrict__ x,
                                               const short* __restrict__ Wt,  // [64][128] bf16
                                               const float* __restrict__ dinv,
                                               bf16* __restrict__ g1, int n) {
  int wave = threadIdx.x >> 6;
  int lane = threadIdx.x & 63;
  int m = lane & 15;
  int quad = lane >> 4;
  int r = blockIdx.x * 64 + wave * 16 + m;

  s8v afr[4];
  if (r < n) {
    const float* ap = x + (size_t)r * 128 + quad * 8;
#pragma unroll
    for (int kc = 0; kc < 4; kc++) {
      float4 u = *(const float4*)(ap + kc * 32);
      float4 v = *(const float4*)(ap + kc * 32 + 4);
      s8v a;
      a[0] = f2b(u.x); a[1] = f2b(u.y); a[2] = f2b(u.z); a[3] = f2b(u.w);
      a[4] = f2b(v.x); a[5] = f2b(v.y); a[6] = f2b(v.z); a[7] = f2b(v.w);
      afr[kc] = a;
    }
  } else {
#pragma unroll
    for (int kc = 0; kc < 4; kc++) afr[kc] = (s8v)(short)0;
  }

  const short* wp = Wt + (size_t)m * 128 + quad * 8;
  s8v bfr[4][4];
#pragma unroll
  for (int nt = 0; nt < 4; nt++)
#pragma unroll
    for (int kc = 0; kc < 4; kc++)
      bfr[nt][kc] = *(const s8v*)(wp + nt * 16 * 128 + kc * 32);

  f4v acc[4] = {f4v{0,0,0,0}, f4v{0,0,0,0}, f4v{0,0,0,0}, f4v{0,0,0,0}};
#pragma unroll
  for (int kc = 0; kc < 4; kc++)
#pragma unroll
    for (int nt = 0; nt < 4; nt++)
      acc[nt] = __builtin_amdgcn_mfma_f32_16x16x32_bf16(afr[kc], bfr[nt][kc], acc[nt], 0, 0, 0);

  int rbase = blockIdx.x * 64 + wave * 16 + quad * 4;
#pragma unroll
  for (int reg = 0; reg < 4; reg++) {
    int rr = rbase + reg;
    if (rr < n) {
      float dv = dinv[rr];
#pragma unroll
      for (int nt = 0; nt < 4; nt++)
        g1[(size_t)rr * 64 + nt * 16 + m] = __float2bfloat16(acc[nt][reg] * dv);
    }
  }
}

// ---- MFMA gemm2: g2[n,32] = dinv[r]*(z1b[n,64] @ W2[64,32]), bf16 out ----
__global__ __launch_bounds__(256) void k_gemm2(const bf16* __restrict__ z1b,
                                               const short* __restrict__ Wt,  // [32][64] bf16
                                               const float* __restrict__ dinv,
                                               short* __restrict__ g2, int n) {
  int wave = threadIdx.x >> 6;
  int lane = threadIdx.x & 63;
  int m = lane & 15;
  int quad = lane >> 4;
  int r = blockIdx.x * 64 + wave * 16 + m;

  s8v afr[2];
  if (r < n) {
    const short* ap = (const short*)z1b + (size_t)r * 64 + quad * 8;
#pragma unroll
    for (int kc = 0; kc < 2; kc++) afr[kc] = *(const s8v*)(ap + kc * 32);
  } else {
#pragma unroll
    for (int kc = 0; kc < 2; kc++) afr[kc] = (s8v)(short)0;
  }

  const short* wp = Wt + (size_t)m * 64 + quad * 8;
  s8v bfr[2][2];
#pragma unroll
  for (int nt = 0; nt < 2; nt++)
#pragma unroll
    for (int kc = 0; kc < 2; kc++)
      bfr[nt][kc] = *(const s8v*)(wp + nt * 16 * 64 + kc * 32);

  f4v acc[2] = {f4v{0,0,0,0}, f4v{0,0,0,0}};
#pragma unroll
  for (int kc = 0; kc < 2; kc++)
#pragma unroll
    for (int nt = 0; nt < 2; nt++)
      acc[nt] = __builtin_amdgcn_mfma_f32_16x16x32_bf16(afr[kc], bfr[nt][kc], acc[nt], 0, 0, 0);

  int rbase = blockIdx.x * 64 + wave * 16 + quad * 4;
#pragma unroll
  for (int reg = 0; reg < 4; reg++) {
    int rr = rbase + reg;
    if (rr < n) {
      float dv = dinv[rr];
#pragma unroll
      for (int nt = 0; nt < 2; nt++)
        g2[(size_t)rr * 32 + nt * 16 + m] = f2b(acc[nt][reg] * dv);
    }
  }
}

// ---- layer-1 aggregate: tile-major, block-level LDS f32 accumulation ----
// One block per 64-dest bucket; whole grid (1563 blocks, 16.6 KB LDS) is
// co-resident, so all blocks stream the SAME 2 MB source tile in lockstep.
#define AGG1_EDGE(P)                                                       \
  do {                                                                     \
    int r_ = (P) & 0x1FFFF;                                                \
    int c_ = (P) >> 17;                                                    \
    int4 pk_ = *(const int4*)(gf + (size_t)r_ * 64);                       \
    float* ap_ = &acc[c_ * 65 + fl * 8];                                   \
    atomicAdd(ap_ + 0, bf_lo(pk_.x)); atomicAdd(ap_ + 1, bf_hi(pk_.x));    \
    atomicAdd(ap_ + 2, bf_lo(pk_.y)); atomicAdd(ap_ + 3, bf_hi(pk_.y));    \
    atomicAdd(ap_ + 4, bf_lo(pk_.z)); atomicAdd(ap_ + 5, bf_hi(pk_.z));    \
    atomicAdd(ap_ + 6, bf_lo(pk_.w)); atomicAdd(ap_ + 7, bf_hi(pk_.w));    \
  } while (0)

__global__ __launch_bounds__(256) void k_gagg1(const int* __restrict__ bbase,
                                               const int* __restrict__ adj,
                                               const float* __restrict__ dinv,
                                               const short* __restrict__ g,   // g1 bf16 [n][64]
                                               const float* __restrict__ bias,
                                               short* __restrict__ z, int n) {
  __shared__ float acc[BNODES * 65];   // pad 65: break c*64 bank alignment
  int b = blockIdx.x, t = threadIdx.x;
  int node_base = b << BSHIFT;
  int lo = bbase[b], hi = bbase[b + 1];
  for (int i = t; i < BNODES * 65; i += 256) acc[i] = 0.f;
  __syncthreads();
  int wave = t >> 6, lane = t & 63;
  int grp = lane >> 3;                 // 0..7: edge slot
  int fl = lane & 7;                   // feature slice: shorts fl*8..fl*8+7
  const short* gf = g + fl * 8;
  int base = lo;
  for (; base + 128 <= hi; base += 128) {   // 32 edges/wave/iter, 4 in flight
    int p0 = adj[base + 0 * 32 + wave * 8 + grp];
    int p1 = adj[base + 1 * 32 + wave * 8 + grp];
    int p2 = adj[base + 2 * 32 + wave * 8 + grp];
    int p3 = adj[base + 3 * 32 + wave * 8 + grp];
    AGG1_EDGE(p0); AGG1_EDGE(p1); AGG1_EDGE(p2); AGG1_EDGE(p3);
  }
  for (int e0 = base + wave * 8; e0 < hi; e0 += 32) {
    int e = e0 + grp;
    if (e < hi) { int p = adj[e]; AGG1_EDGE(p); }
  }
  __syncthreads();
  // epilogue: self-loop + bias + relu + dinv scale; 512 (node,f8) slots
  for (int sIdx = t; sIdx < BNODES * 8; sIdx += 256) {
    int nd = sIdx >> 3, f8 = sIdx & 7;
    int node = node_base + nd;
    if (node >= n) continue;
    int4 pk = *(const int4*)(g + (size_t)node * 64 + f8 * 8);   // self-loop
    float d = dinv[node];
    const float* ap = &acc[nd * 65 + f8 * 8];
    float4 b0 = *(const float4*)(bias + f8 * 8);
    float4 b1 = *(const float4*)(bias + f8 * 8 + 4);
    float v0 = fmaxf(fmaf(d, ap[0] + bf_lo(pk.x), b0.x), 0.f);
    float v1 = fmaxf(fmaf(d, ap[1] + bf_hi(pk.x), b0.y), 0.f);
    float v2 = fmaxf(fmaf(d, ap[2] + bf_lo(pk.y), b0.z), 0.f);
    float v3 = fmaxf(fmaf(d, ap[3] + bf_hi(pk.y), b0.w), 0.f);
    float v4 = fmaxf(fmaf(d, ap[4] + bf_lo(pk.z), b1.x), 0.f);
    float v5 = fmaxf(fmaf(d, ap[5] + bf_hi(pk.z), b1.y), 0.f);
    float v6 = fmaxf(fmaf(d, ap[6] + bf_lo(pk.w), b1.z), 0.f);
    float v7 = fmaxf(fmaf(d, ap[7] + bf_hi(pk.w), b1.w), 0.f);
    int4 out;
    out.x = (int)(unsigned short)f2b(v0) | ((int)f2b(v1) << 16);
    out.y = (int)(unsigned short)f2b(v2) | ((int)f2b(v3) << 16);
    out.z = (int)(unsigned short)f2b(v4) | ((int)f2b(v5) << 16);
    out.w = (int)(unsigned short)f2b(v6) | ((int)f2b(v7) << 16);
    *(int4*)(z + (size_t)node * 64 + f8 * 8) = out;
  }
}

// ---- layer-2 aggregate: same structure, 32 feats (4 lanes x 16B per edge) ----
#define AGG2_EDGE(P)                                                       \
  do {                                                                     \
    int r_ = (P) & 0x1FFFF;                                                \
    int c_ = (P) >> 17;                                                    \
    int4 pk_ = *(const int4*)(gf + (size_t)r_ * 32);                       \
    float* ap_ = &acc[c_ * 33 + fl * 8];                                   \
    atomicAdd(ap_ + 0, bf_lo(pk_.x)); atomicAdd(ap_ + 1, bf_hi(pk_.x));    \
    atomicAdd(ap_ + 2, bf_lo(pk_.y)); atomicAdd(ap_ + 3, bf_hi(pk_.y));    \
    atomicAdd(ap_ + 4, bf_lo(pk_.z)); atomicAdd(ap_ + 5, bf_hi(pk_.z));    \
    atomicAdd(ap_ + 6, bf_lo(pk_.w)); atomicAdd(ap_ + 7, bf_hi(pk_.w));    \
  } while (0)

__global__ __launch_bounds__(256) void k_gagg2(const int* __restrict__ bbase,
                                               const int* __restrict__ adj,
                                               const float* __restrict__ dinv,
                                               const short* __restrict__ g,   // g2 bf16 [n][32]
                                               const float* __restrict__ bias,
                                               float* __restrict__ z, int n) {
  __shared__ float acc[BNODES * 33];
  int b = blockIdx.x, t = threadIdx.x;
  int node_base = b << BSHIFT;
  int lo = bbase[b], hi = bbase[b + 1];
  for (int i = t; i < BNODES * 33; i += 256) acc[i] = 0.f;
  __syncthreads();
  int wave = t >> 6, lane = t & 63;
  int grp = lane >> 2;                 // 0..15: edge slot
  int fl = lane & 3;                   // feature slice: shorts fl*8..fl*8+7
  const short* gf = g + fl * 8;
  int base = lo;
  for (; base + 256 <= hi; base += 256) {   // 64 edges/wave/iter, 4 in flight
    int p0 = adj[base + 0 * 64 + wave * 16 + grp];
    int p1 = adj[base + 1 * 64 + wave * 16 + grp];
    int p2 = adj[base + 2 * 64 + wave * 16 + grp];
    int p3 = adj[base + 3 * 64 + wave * 16 + grp];
    AGG2_EDGE(p0); AGG2_EDGE(p1); AGG2_EDGE(p2); AGG2_EDGE(p3);
  }
  for (int e0 = base + wave * 16; e0 < hi; e0 += 64) {
    int e = e0 + grp;
    if (e < hi) { int p = adj[e]; AGG2_EDGE(p); }
  }
  __syncthreads();
  // epilogue: 256 (node,f8) slots, exactly 1 per thread
  int nd = t >> 2, f8 = t & 3;
  int node = node_base + nd;
  if (node < n) {
    int4 pk = *(const int4*)(g + (size_t)node * 32 + f8 * 8);   // self-loop
    float d = dinv[node];
    const float* ap = &acc[nd * 33 + f8 * 8];
    float4 b0 = *(const float4*)(bias + f8 * 8);
    float4 b1 = *(const float4*)(bias + f8 * 8 + 4);
    float4 o0, o1;
    o0.x = fmaf(d, ap[0] + bf_lo(pk.x), b0.x);
    o0.y = fmaf(d, ap[1] + bf_hi(pk.x), b0.y);
    o0.z = fmaf(d, ap[2] + bf_lo(pk.y), b0.z);
    o0.w = fmaf(d, ap[3] + bf_hi(pk.y), b0.w);
    o1.x = fmaf(d, ap[4] + bf_lo(pk.z), b1.x);
    o1.y = fmaf(d, ap[5] + bf_hi(pk.z), b1.y);
    o1.z = fmaf(d, ap[6] + bf_lo(pk.w), b1.z);
    o1.w = fmaf(d, ap[7] + bf_hi(pk.w), b1.w);
    *(float4*)(z + (size_t)node * 32 + f8 * 8) = o0;
    *(float4*)(z + (size_t)node * 32 + f8 * 8 + 4) = o1;
  }
}

// ---- link decode: half-wave per label edge, shuffle reduce, fp32 out ----
__global__ __launch_bounds__(256) void k_decode(const int* __restrict__ ea,
                                                const int* __restrict__ eb,
                                                const float* __restrict__ z2,
                                                float* __restrict__ out, int EL) {
  int lane = threadIdx.x & 31;
  int e = blockIdx.x * 8 + (threadIdx.x >> 5);
  if (e >= EL) return;
  int a = ea[e], b = eb[e];
  float p = z2[a * 32 + lane] * z2[b * 32 + lane];
  p += __shfl_down(p, 16);
  p += __shfl_down(p, 8);
  p += __shfl_down(p, 4);
  p += __shfl_down(p, 2);
  p += __shfl_down(p, 1);
  if (lane == 0) out[e] = p;
}

extern "C" void kernel_launch(void* const* d_in, const int* in_sizes, int n_in,
                              void* d_out, int out_size, void* d_ws, size_t ws_size,
                              hipStream_t stream) {
  const float* x   = (const float*)d_in[0];
  const float* W1  = (const float*)d_in[1];
  const float* b1  = (const float*)d_in[2];
  const float* W2  = (const float*)d_in[3];
  const float* b2  = (const float*)d_in[4];
  const int*   ei  = (const int*)d_in[5];   // [2,E]: row=ei[0..E), col=ei[E..2E)
  const int*   eli = (const int*)d_in[6];   // [2,EL]

  const int N  = in_sizes[0] / 128;  // 100000
  const int E  = in_sizes[5] / 2;    // 3200000
  const int EL = in_sizes[6] / 2;    // 200000
  const int* row = ei;
  const int* col = ei + E;
  const int NBUCK = (N + BNODES - 1) / BNODES;   // 1563
  const int NCHNK = (E + CHUNK - 1) / CHUNK;     // 782

  // workspace (~57 MB)
  char* ws = (char*)d_ws;
  size_t off = 0;
  auto take = [&](size_t bytes) { char* p = ws + off; off += (bytes + 255) & ~(size_t)255; return p; };
  float* dinv      = (float*)take((size_t)N * 4);
  int*   btot      = (int*)take((size_t)NBUCK * 4);
  int*   bbase     = (int*)take((size_t)(NBUCK + 1) * 4);
  short* Wt1       = (short*)take((size_t)64 * 128 * 2);
  short* Wt2       = (short*)take((size_t)32 * 64 * 2);
  int*   chist     = (int*)take((size_t)NCHNK * NBUCK * 4);   // 4.89 MB
  int*   adj       = (int*)take((size_t)E * 4);               // 12.8 MB (sorted in place)
  char*  bufH      = take((size_t)N * 64 * 2);                // g1 bf16 / g2 bf16
  short* z1b       = (short*)take((size_t)N * 64 * 2);        // relu'd, bf16
  float* z2        = (float*)take((size_t)N * 32 * 4);
  (void)ws_size; (void)n_in; (void)out_size;

  bf16*  g1 = (bf16*)bufH;
  short* g2 = (short*)bufH;   // aliases g1 (g1 dead when g2 written)

  k_prepW     <<<32, 256, 0, stream>>>(W1, W2, Wt1, Wt2);
  k_hist      <<<NCHNK, 256, 0, stream>>>(col, E, NBUCK, chist);
  k_scanbuck  <<<NBUCK, 256, 0, stream>>>(chist, NCHNK, NBUCK, btot);
  k_scanbase  <<<1, 512, 0, stream>>>(btot, NBUCK, bbase);
  k_binpass   <<<NCHNK, 256, 0, stream>>>(row, col, E, NBUCK, bbase, chist, adj);
  k_bucketsort<<<NBUCK, 256, 0, stream>>>(bbase, adj, dinv, N);

  k_gemm1<<<(N + 63) / 64, 256, 0, stream>>>(x, Wt1, dinv, g1, N);
  k_gagg1<<<NBUCK, 256, 0, stream>>>(bbase, adj, dinv, (const short*)g1, b1, z1b, N);

  k_gemm2<<<(N + 63) / 64, 256, 0, stream>>>((const bf16*)z1b, Wt2, dinv, g2, N);
  k_gagg2<<<NBUCK, 256, 0, stream>>>(bbase, adj, dinv, g2, b2, z2, N);

  k_decode<<<(EL + 7) / 8, 256, 0, stream>>>(eli, eli + EL, z2, (float*)d_out, EL);
}

// Round 3
// 310.819 us; speedup vs baseline: 6.4807x; 6.4807x over previous
//
#include <hip/hip_runtime.h>
#include <hip/hip_bf16.h>

typedef __hip_bfloat16 bf16;
typedef short s8v __attribute__((ext_vector_type(8)));   // 8 bf16 in 4 VGPRs
typedef float f4v __attribute__((ext_vector_type(4)));   // MFMA 16x16 C/D frag

__device__ __forceinline__ short f2b(float f) {
  bf16 h = __float2bfloat16(f);
  return *reinterpret_cast<short*>(&h);
}
// accumulate 4 bf16 (packed in 2 dwords, memory order) into float4
__device__ __forceinline__ void bf4_acc(int lo, int hi, float4& a) {
  a.x += __int_as_float(lo << 16);
  a.y += __int_as_float(lo & 0xFFFF0000);
  a.z += __int_as_float(hi << 16);
  a.w += __int_as_float(hi & 0xFFFF0000);
}

#define BSHIFT 8        // 256 dest nodes per bucket
#define BNODES 256
#define CHUNK 4096      // edges per chunk
#define SORT_CAP 12288  // bucket-sort LDS capacity (48 KB); mean bucket = 8192
#define TSHIFT 15       // source tile = 32K rows = 4 MB of g1 (fits per-XCD L2)

// ---- phase 1: per-chunk bucket histogram (LDS atomics only) ----
__global__ __launch_bounds__(256) void k_hist(const int* __restrict__ col, int E,
                                              int nbuck, int* __restrict__ chist) {
  __shared__ int hist[512];
  int t = threadIdx.x;
  hist[t] = 0; hist[t + 256] = 0;
  __syncthreads();
  int e0 = blockIdx.x * CHUNK;
#pragma unroll
  for (int i = 0; i < 16; i++) {
    int e = e0 + i * 256 + t;
    if (e < E) atomicAdd(&hist[col[e] >> BSHIFT], 1);
  }
  __syncthreads();
  int* out = chist + (size_t)blockIdx.x * nbuck;
  for (int b = t; b < nbuck; b += 256) out[b] = hist[b];  // coalesced
}

// ---- phase 2: per-bucket exclusive scan over chunks (in place) ----
__global__ __launch_bounds__(256) void k_scanbuck(int* __restrict__ chist, int nchnk,
                                                  int nbuck, int* __restrict__ btot) {
  __shared__ int sm[256];
  int b = blockIdx.x, t = threadIdx.x;
  int per = (nchnk + 255) / 256;
  int lo = t * per, hi = min(lo + per, nchnk);
  int s = 0;
  for (int i = lo; i < hi; i++) s += chist[(size_t)i * nbuck + b];
  sm[t] = s;
  __syncthreads();
  for (int d = 1; d < 256; d <<= 1) {
    int x = (t >= d) ? sm[t - d] : 0;
    __syncthreads();
    sm[t] += x;
    __syncthreads();
  }
  int off = (t == 0) ? 0 : sm[t - 1];
  for (int i = lo; i < hi; i++) {
    int c = chist[(size_t)i * nbuck + b];
    chist[(size_t)i * nbuck + b] = off;
    off += c;
  }
  if (t == 255) btot[b] = sm[255];
}

// ---- phase 3: scan bucket totals (parallel LDS scan) ----
__global__ __launch_bounds__(512) void k_scanbase(const int* __restrict__ btot, int nbuck,
                                                  int* __restrict__ bbase,
                                                  int* __restrict__ row_start, int n) {
  __shared__ int sm[512];
  int t = threadIdx.x;
  int v = (t < nbuck) ? btot[t] : 0;
  sm[t] = v;
  __syncthreads();
  for (int d = 1; d < 512; d <<= 1) {   // Hillis-Steele inclusive
    int x = (t >= d) ? sm[t - d] : 0;
    __syncthreads();
    sm[t] += x;
    __syncthreads();
  }
  if (t < nbuck) bbase[t] = sm[t] - v;  // exclusive prefix
  if (t == nbuck - 1) {
    bbase[nbuck] = sm[t];
    row_start[n] = sm[t];  // == E
  }
}

// ---- phase 4: grouped scatter into bucket-sorted adjTmp, NO global atomics ----
// adjTmp entry: r | (c_low << 17)
__global__ __launch_bounds__(256) void k_binpass(const int* __restrict__ row,
                                                 const int* __restrict__ col, int E,
                                                 int nbuck,
                                                 const int* __restrict__ bbase,
                                                 const int* __restrict__ chist,
                                                 int* __restrict__ adjTmp) {
  __shared__ int hist[512];
  __shared__ int base[512];
  __shared__ int lcur[512];
  __shared__ int gbase[512];
  __shared__ int psum[256];
  __shared__ int stage[CHUNK];
  __shared__ unsigned short sbkt[CHUNK];
  __shared__ int s_total;
  int t = threadIdx.x;
  int e0 = blockIdx.x * CHUNK;

  hist[t] = 0; hist[t + 256] = 0;
  __syncthreads();

  int pk[16], bk[16];
#pragma unroll
  for (int i = 0; i < 16; i++) {
    int e = e0 + i * 256 + t;
    if (e < E) {
      int c = col[e];
      int r = row[e];
      bk[i] = c >> BSHIFT;
      pk[i] = r | ((c & (BNODES - 1)) << 17);
      atomicAdd(&hist[bk[i]], 1);
    } else bk[i] = -1;
  }
  __syncthreads();
  int a0 = hist[2 * t], a1 = hist[2 * t + 1];
  psum[t] = a0 + a1;
  __syncthreads();
  for (int d = 1; d < 256; d <<= 1) {
    int v = (t >= d) ? psum[t - d] : 0;
    __syncthreads();
    psum[t] += v;
    __syncthreads();
  }
  int pref = (t == 0) ? 0 : psum[t - 1];
  base[2 * t] = pref;          lcur[2 * t] = pref;
  base[2 * t + 1] = pref + a0; lcur[2 * t + 1] = pref + a0;
  if (t == 255) s_total = psum[255];
  const int* coff = chist + (size_t)blockIdx.x * nbuck;
  for (int b = t; b < nbuck; b += 256) gbase[b] = bbase[b] + coff[b];
  __syncthreads();
#pragma unroll
  for (int i = 0; i < 16; i++) {
    if (bk[i] >= 0) {
      int pos = atomicAdd(&lcur[bk[i]], 1);
      stage[pos] = pk[i];
      sbkt[pos] = (unsigned short)bk[i];
    }
  }
  __syncthreads();
  int total = s_total;
  for (int i = t; i < total; i += 256) {
    int b = sbkt[i];
    adjTmp[gbase[b] + (i - base[b])] = stage[i];
  }
}

// ---- phase 5: per-bucket sort, key = (c_low, src_tile); emits dinv, row_start,
//      adj sorted by dest node with each row's edges ordered by 4MB source tile ----
__global__ __launch_bounds__(256) void k_bucketsort(const int* __restrict__ bbase,
                                                    const int* __restrict__ adjTmp,
                                                    int* __restrict__ adj,
                                                    int* __restrict__ row_start,
                                                    float* __restrict__ dinv, int n) {
  __shared__ int cnt[1024];
  __shared__ int sc[256];
  __shared__ int cur[1024];
  __shared__ int stage[SORT_CAP];
  int b = blockIdx.x, t = threadIdx.x;
  int node_base = b << BSHIFT;
  int nnode = min(BNODES, n - node_base);
  int seg_base = bbase[b];
  int cntE = bbase[b + 1] - seg_base;
  cnt[t] = 0; cnt[t + 256] = 0; cnt[t + 512] = 0; cnt[t + 768] = 0;
  __syncthreads();
  for (int i = t; i < cntE; i += 256) {
    int p = adjTmp[seg_base + i];
    int key = (((p >> 17) & 255) << 2) | ((p >> TSHIFT) & 3);
    atomicAdd(&cnt[key], 1);
  }
  __syncthreads();
  int c0 = cnt[4 * t], c1 = cnt[4 * t + 1], c2 = cnt[4 * t + 2], c3 = cnt[4 * t + 3];
  int myc = c0 + c1 + c2 + c3;        // node degree
  sc[t] = myc;
  __syncthreads();
  for (int d = 1; d < 256; d <<= 1) {
    int x = (t >= d) ? sc[t - d] : 0;
    __syncthreads();
    sc[t] += x;
    __syncthreads();
  }
  int excl = (t == 0) ? 0 : sc[t - 1];
  cur[4 * t] = excl;
  cur[4 * t + 1] = excl + c0;
  cur[4 * t + 2] = excl + c0 + c1;
  cur[4 * t + 3] = excl + c0 + c1 + c2;
  if (t < nnode) {
    row_start[node_base + t] = seg_base + excl;
    dinv[node_base + t] = rsqrtf((float)myc + 1.0f);  // +1 = self-loop
  }
  __syncthreads();
  if (cntE <= SORT_CAP) {
    for (int i = t; i < cntE; i += 256) {
      int p = adjTmp[seg_base + i];
      int key = (((p >> 17) & 255) << 2) | ((p >> TSHIFT) & 3);
      int pos = atomicAdd(&cur[key], 1);
      stage[pos] = p & 0x1FFFF;
    }
    __syncthreads();
    for (int i = t; i < cntE; i += 256) adj[seg_base + i] = stage[i];
  } else {
    // fallback (statistically never)
    for (int i = t; i < cntE; i += 256) {
      int p = adjTmp[seg_base + i];
      int key = (((p >> 17) & 255) << 2) | ((p >> TSHIFT) & 3);
      int pos = atomicAdd(&cur[key], 1);
      adj[seg_base + pos] = p & 0x1FFFF;
    }
  }
}

// ---- weight prep: Wt1[64][128] = W1^T bf16, Wt2[32][64] = W2^T bf16 ----
__global__ __launch_bounds__(256) void k_prepW(const float* __restrict__ W1,
                                               const float* __restrict__ W2,
                                               short* __restrict__ Wt1,
                                               short* __restrict__ Wt2) {
  int t = blockIdx.x * 256 + threadIdx.x;
  if (t < 128 * 64) { int k = t >> 6, c = t & 63; Wt1[c * 128 + k] = f2b(W1[t]); }
  if (t < 64 * 32)  { int k = t >> 5, c = t & 31; Wt2[c * 64 + k] = f2b(W2[t]); }
}

// ---- MFMA gemm1: g1[n,64] = dinv[r]*(x[n,128] @ W1[128,64]), bf16 out ----
__global__ __launch_bounds__(256) void k_gemm1(const float* __restrict__ x,
                                               const short* __restrict__ Wt,  // [64][128] bf16
                                               const float* __restrict__ dinv,
                                               bf16* __restrict__ g1, int n) {
  int wave = threadIdx.x >> 6;
  int lane = threadIdx.x & 63;
  int m = lane & 15;
  int quad = lane >> 4;
  int r = blockIdx.x * 64 + wave * 16 + m;

  s8v afr[4];
  if (r < n) {
    const float* ap = x + (size_t)r * 128 + quad * 8;
#pragma unroll
    for (int kc = 0; kc < 4; kc++) {
      float4 u = *(const float4*)(ap + kc * 32);
      float4 v = *(const float4*)(ap + kc * 32 + 4);
      s8v a;
      a[0] = f2b(u.x); a[1] = f2b(u.y); a[2] = f2b(u.z); a[3] = f2b(u.w);
      a[4] = f2b(v.x); a[5] = f2b(v.y); a[6] = f2b(v.z); a[7] = f2b(v.w);
      afr[kc] = a;
    }
  } else {
#pragma unroll
    for (int kc = 0; kc < 4; kc++) afr[kc] = (s8v)(short)0;
  }

  const short* wp = Wt + (size_t)m * 128 + quad * 8;
  s8v bfr[4][4];
#pragma unroll
  for (int nt = 0; nt < 4; nt++)
#pragma unroll
    for (int kc = 0; kc < 4; kc++)
      bfr[nt][kc] = *(const s8v*)(wp + nt * 16 * 128 + kc * 32);

  f4v acc[4] = {f4v{0,0,0,0}, f4v{0,0,0,0}, f4v{0,0,0,0}, f4v{0,0,0,0}};
#pragma unroll
  for (int kc = 0; kc < 4; kc++)
#pragma unroll
    for (int nt = 0; nt < 4; nt++)
      acc[nt] = __builtin_amdgcn_mfma_f32_16x16x32_bf16(afr[kc], bfr[nt][kc], acc[nt], 0, 0, 0);

  int rbase = blockIdx.x * 64 + wave * 16 + quad * 4;
#pragma unroll
  for (int reg = 0; reg < 4; reg++) {
    int rr = rbase + reg;
    if (rr < n) {
      float dv = dinv[rr];
#pragma unroll
      for (int nt = 0; nt < 4; nt++)
        g1[(size_t)rr * 64 + nt * 16 + m] = __float2bfloat16(acc[nt][reg] * dv);
    }
  }
}

// ---- MFMA gemm2: g2[n,32] = dinv[r]*(z1b[n,64] @ W2[64,32]), bf16 out ----
__global__ __launch_bounds__(256) void k_gemm2(const bf16* __restrict__ z1b,
                                               const short* __restrict__ Wt,  // [32][64] bf16
                                               const float* __restrict__ dinv,
                                               short* __restrict__ g2, int n) {
  int wave = threadIdx.x >> 6;
  int lane = threadIdx.x & 63;
  int m = lane & 15;
  int quad = lane >> 4;
  int r = blockIdx.x * 64 + wave * 16 + m;

  s8v afr[2];
  if (r < n) {
    const short* ap = (const short*)z1b + (size_t)r * 64 + quad * 8;
#pragma unroll
    for (int kc = 0; kc < 2; kc++) afr[kc] = *(const s8v*)(ap + kc * 32);
  } else {
#pragma unroll
    for (int kc = 0; kc < 2; kc++) afr[kc] = (s8v)(short)0;
  }

  const short* wp = Wt + (size_t)m * 64 + quad * 8;
  s8v bfr[2][2];
#pragma unroll
  for (int nt = 0; nt < 2; nt++)
#pragma unroll
    for (int kc = 0; kc < 2; kc++)
      bfr[nt][kc] = *(const s8v*)(wp + nt * 16 * 64 + kc * 32);

  f4v acc[2] = {f4v{0,0,0,0}, f4v{0,0,0,0}};
#pragma unroll
  for (int kc = 0; kc < 2; kc++)
#pragma unroll
    for (int nt = 0; nt < 2; nt++)
      acc[nt] = __builtin_amdgcn_mfma_f32_16x16x32_bf16(afr[kc], bfr[nt][kc], acc[nt], 0, 0, 0);

  int rbase = blockIdx.x * 64 + wave * 16 + quad * 4;
#pragma unroll
  for (int reg = 0; reg < 4; reg++) {
    int rr = rbase + reg;
    if (rr < n) {
      float dv = dinv[rr];
#pragma unroll
      for (int nt = 0; nt < 2; nt++)
        g2[(size_t)rr * 32 + nt * 16 + m] = f2b(acc[nt][reg] * dv);
    }
  }
}

// ---- layer-1 aggregate: 1 wave/dest, 8 lanes x 16B per edge (8 edges/inst) ----
// r12: 4-deep rotating software pipeline. Preload issues the whole typical row
// (32 edges) back-to-back; each phase consumes group P while refilling it for
// +32 edges ahead. Loads exec-mask-predicated (no clamp duds, no wasted fetch).
// Per-lane accumulation order identical to round-9 body (same absmax).
__global__ __launch_bounds__(256) void k_gagg1(const int* __restrict__ row_start,
                                               const int* __restrict__ adj,
                                               const float* __restrict__ dinv,
                                               const short* __restrict__ g,   // g1 bf16 [n][64]
                                               const float* __restrict__ bias,
                                               short* __restrict__ z, int n) {
  int wave = threadIdx.x >> 6;
  int lane = threadIdx.x & 63;
  int grp = lane >> 3;     // 0..7: edge slot
  int fl = lane & 7;       // feature slice: shorts fl*8..fl*8+7 (16 B)
  int c = blockIdx.x * 4 + wave;
  if (c >= n) return;
  int start = row_start[c], end = row_start[c + 1];
  const short* gf = g + fl * 8;
  float4 a0 = {0.f,0.f,0.f,0.f}, a1 = {0.f,0.f,0.f,0.f};
  int4 q0 = {0,0,0,0}, q1 = {0,0,0,0}, q2 = {0,0,0,0}, q3 = {0,0,0,0};
  {
    int e = start + grp;
    if (e      < end) { int r = adj[e];      q0 = *(const int4*)(gf + (size_t)r * 64); }
    if (e + 8  < end) { int r = adj[e + 8];  q1 = *(const int4*)(gf + (size_t)r * 64); }
    if (e + 16 < end) { int r = adj[e + 16]; q2 = *(const int4*)(gf + (size_t)r * 64); }
    if (e + 24 < end) { int r = adj[e + 24]; q3 = *(const int4*)(gf + (size_t)r * 64); }
  }
  for (int base = start; base < end; base += 32) {
    {  // phase 0
      int e = base + grp;
      int4 q = q0;
      int ep = e + 32;
      if (ep < end) { int rp = adj[ep]; q0 = *(const int4*)(gf + (size_t)rp * 64); }
      if (e < end) { bf4_acc(q.x, q.y, a0); bf4_acc(q.z, q.w, a1); }
    }
    {  // phase 1
      int e = base + 8 + grp;
      int4 q = q1;
      int ep = e + 32;
      if (ep < end) { int rp = adj[ep]; q1 = *(const int4*)(gf + (size_t)rp * 64); }
      if (e < end) { bf4_acc(q.x, q.y, a0); bf4_acc(q.z, q.w, a1); }
    }
    {  // phase 2
      int e = base + 16 + grp;
      int4 q = q2;
      int ep = e + 32;
      if (ep < end) { int rp = adj[ep]; q2 = *(const int4*)(gf + (size_t)rp * 64); }
      if (e < end) { bf4_acc(q.x, q.y, a0); bf4_acc(q.z, q.w, a1); }
    }
    {  // phase 3
      int e = base + 24 + grp;
      int4 q = q3;
      int ep = e + 32;
      if (ep < end) { int rp = adj[ep]; q3 = *(const int4*)(gf + (size_t)rp * 64); }
      if (e < end) { bf4_acc(q.x, q.y, a0); bf4_acc(q.z, q.w, a1); }
    }
  }
  // reduce 8 edge slots (lane bits 3..5)
#pragma unroll
  for (int s = 8; s <= 32; s <<= 1) {
    a0.x += __shfl_xor(a0.x, s); a0.y += __shfl_xor(a0.y, s);
    a0.z += __shfl_xor(a0.z, s); a0.w += __shfl_xor(a0.w, s);
    a1.x += __shfl_xor(a1.x, s); a1.y += __shfl_xor(a1.y, s);
    a1.z += __shfl_xor(a1.z, s); a1.w += __shfl_xor(a1.w, s);
  }
  if (grp == 0) {
    int4 pk = *(const int4*)(g + c * 64 + fl * 8);   // self-loop
    bf4_acc(pk.x, pk.y, a0);
    bf4_acc(pk.z, pk.w, a1);
    float d = dinv[c];
    float4 b0 = *(const float4*)(bias + fl * 8);
    float4 b1 = *(const float4*)(bias + fl * 8 + 4);
    float v0 = fmaxf(fmaf(d, a0.x, b0.x), 0.f);
    float v1 = fmaxf(fmaf(d, a0.y, b0.y), 0.f);
    float v2 = fmaxf(fmaf(d, a0.z, b0.z), 0.f);
    float v3 = fmaxf(fmaf(d, a0.w, b0.w), 0.f);
    float v4 = fmaxf(fmaf(d, a1.x, b1.x), 0.f);
    float v5 = fmaxf(fmaf(d, a1.y, b1.y), 0.f);
    float v6 = fmaxf(fmaf(d, a1.z, b1.z), 0.f);
    float v7 = fmaxf(fmaf(d, a1.w, b1.w), 0.f);
    int4 out;
    out.x = (int)(unsigned short)f2b(v0) | ((int)f2b(v1) << 16);
    out.y = (int)(unsigned short)f2b(v2) | ((int)f2b(v3) << 16);
    out.z = (int)(unsigned short)f2b(v4) | ((int)f2b(v5) << 16);
    out.w = (int)(unsigned short)f2b(v6) | ((int)f2b(v7) << 16);
    *(int4*)(z + c * 64 + fl * 8) = out;
  }
}

// ---- layer-2 aggregate: 1 wave/dest, 4 lanes x 16B per edge (16 edges/inst) ----
// r12: same 4-deep rotating pipeline, step 16 (64 edges in flight at preload).
__global__ __launch_bounds__(256) void k_gagg2(const int* __restrict__ row_start,
                                               const int* __restrict__ adj,
                                               const float* __restrict__ dinv,
                                               const short* __restrict__ g,   // g2 bf16 [n][32]
                                               const float* __restrict__ bias,
                                               float* __restrict__ z, int n) {
  int wave = threadIdx.x >> 6;
  int lane = threadIdx.x & 63;
  int grp = lane >> 2;     // 0..15: edge slot
  int fl = lane & 3;       // feature slice: shorts fl*8..fl*8+7 (16 B)
  int c = blockIdx.x * 4 + wave;
  if (c >= n) return;
  int start = row_start[c], end = row_start[c + 1];
  const short* gf = g + fl * 8;
  float4 a0 = {0.f,0.f,0.f,0.f}, a1 = {0.f,0.f,0.f,0.f};
  int4 q0 = {0,0,0,0}, q1 = {0,0,0,0}, q2 = {0,0,0,0}, q3 = {0,0,0,0};
  {
    int e = start + grp;
    if (e      < end) { int r = adj[e];      q0 = *(const int4*)(gf + (size_t)r * 32); }
    if (e + 16 < end) { int r = adj[e + 16]; q1 = *(const int4*)(gf + (size_t)r * 32); }
    if (e + 32 < end) { int r = adj[e + 32]; q2 = *(const int4*)(gf + (size_t)r * 32); }
    if (e + 48 < end) { int r = adj[e + 48]; q3 = *(const int4*)(gf + (size_t)r * 32); }
  }
  for (int base = start; base < end; base += 64) {
    {  // phase 0
      int e = base + grp;
      int4 q = q0;
      int ep = e + 64;
      if (ep < end) { int rp = adj[ep]; q0 = *(const int4*)(gf + (size_t)rp * 32); }
      if (e < end) { bf4_acc(q.x, q.y, a0); bf4_acc(q.z, q.w, a1); }
    }
    {  // phase 1
      int e = base + 16 + grp;
      int4 q = q1;
      int ep = e + 64;
      if (ep < end) { int rp = adj[ep]; q1 = *(const int4*)(gf + (size_t)rp * 32); }
      if (e < end) { bf4_acc(q.x, q.y, a0); bf4_acc(q.z, q.w, a1); }
    }
    {  // phase 2
      int e = base + 32 + grp;
      int4 q = q2;
      int ep = e + 64;
      if (ep < end) { int rp = adj[ep]; q2 = *(const int4*)(gf + (size_t)rp * 32); }
      if (e < end) { bf4_acc(q.x, q.y, a0); bf4_acc(q.z, q.w, a1); }
    }
    {  // phase 3
      int e = base + 48 + grp;
      int4 q = q3;
      int ep = e + 64;
      if (ep < end) { int rp = adj[ep]; q3 = *(const int4*)(gf + (size_t)rp * 32); }
      if (e < end) { bf4_acc(q.x, q.y, a0); bf4_acc(q.z, q.w, a1); }
    }
  }
  // reduce 16 edge slots (lane bits 2..5)
#pragma unroll
  for (int s = 4; s <= 32; s <<= 1) {
    a0.x += __shfl_xor(a0.x, s); a0.y += __shfl_xor(a0.y, s);
    a0.z += __shfl_xor(a0.z, s); a0.w += __shfl_xor(a0.w, s);
    a1.x += __shfl_xor(a1.x, s); a1.y += __shfl_xor(a1.y, s);
    a1.z += __shfl_xor(a1.z, s); a1.w += __shfl_xor(a1.w, s);
  }
  if (grp == 0) {
    int4 pk = *(const int4*)(g + c * 32 + fl * 8);   // self-loop
    bf4_acc(pk.x, pk.y, a0);
    bf4_acc(pk.z, pk.w, a1);
    float d = dinv[c];
    float4 b0 = *(const float4*)(bias + fl * 8);
    float4 b1 = *(const float4*)(bias + fl * 8 + 4);
    float4 o0, o1;
    o0.x = fmaf(d, a0.x, b0.x); o0.y = fmaf(d, a0.y, b0.y);
    o0.z = fmaf(d, a0.z, b0.z); o0.w = fmaf(d, a0.w, b0.w);
    o1.x = fmaf(d, a1.x, b1.x); o1.y = fmaf(d, a1.y, b1.y);
    o1.z = fmaf(d, a1.z, b1.z); o1.w = fmaf(d, a1.w, b1.w);
    *(float4*)(z + c * 32 + fl * 8) = o0;
    *(float4*)(z + c * 32 + fl * 8 + 4) = o1;
  }
}

// ---- link decode: half-wave per label edge, shuffle reduce, fp32 out ----
__global__ __launch_bounds__(256) void k_decode(const int* __restrict__ ea,
                                                const int* __restrict__ eb,
                                                const float* __restrict__ z2,
                                                float* __restrict__ out, int EL) {
  int lane = threadIdx.x & 31;
  int e = blockIdx.x * 8 + (threadIdx.x >> 5);
  if (e >= EL) return;
  int a = ea[e], b = eb[e];
  float p = z2[a * 32 + lane] * z2[b * 32 + lane];
  p += __shfl_down(p, 16);
  p += __shfl_down(p, 8);
  p += __shfl_down(p, 4);
  p += __shfl_down(p, 2);
  p += __shfl_down(p, 1);
  if (lane == 0) out[e] = p;
}

extern "C" void kernel_launch(void* const* d_in, const int* in_sizes, int n_in,
                              void* d_out, int out_size, void* d_ws, size_t ws_size,
                              hipStream_t stream) {
  const float* x   = (const float*)d_in[0];
  const float* W1  = (const float*)d_in[1];
  const float* b1  = (const float*)d_in[2];
  const float* W2  = (const float*)d_in[3];
  const float* b2  = (const float*)d_in[4];
  const int*   ei  = (const int*)d_in[5];   // [2,E]: row=ei[0..E), col=ei[E..2E)
  const int*   eli = (const int*)d_in[6];   // [2,EL]

  const int N  = in_sizes[0] / 128;  // 100000
  const int E  = in_sizes[5] / 2;    // 3200000
  const int EL = in_sizes[6] / 2;    // 200000
  const int* row = ei;
  const int* col = ei + E;
  const int NBUCK = (N + BNODES - 1) / BNODES;   // 391
  const int NCHNK = (E + CHUNK - 1) / CHUNK;     // 782

  // workspace (~60 MB)
  char* ws = (char*)d_ws;
  size_t off = 0;
  auto take = [&](size_t bytes) { char* p = ws + off; off += (bytes + 255) & ~(size_t)255; return p; };
  float* dinv      = (float*)take((size_t)N * 4);
  int*   row_start = (int*)take((size_t)(N + 1) * 4);
  int*   btot      = (int*)take((size_t)NBUCK * 4);
  int*   bbase     = (int*)take((size_t)(NBUCK + 1) * 4);
  short* Wt1       = (short*)take((size_t)64 * 128 * 2);
  short* Wt2       = (short*)take((size_t)32 * 64 * 2);
  int*   chist     = (int*)take((size_t)NCHNK * NBUCK * 4);   // 1.22 MB
  int*   adjTmp    = (int*)take((size_t)E * 4);               // 12.8 MB
  int*   adj       = (int*)take((size_t)E * 4);               // 12.8 MB
  char*  bufH      = take((size_t)N * 64 * 2);                // g1 bf16 / g2 bf16
  short* z1b       = (short*)take((size_t)N * 64 * 2);        // relu'd, bf16
  float* z2        = (float*)take((size_t)N * 32 * 4);
  (void)ws_size; (void)n_in; (void)out_size;

  bf16*  g1 = (bf16*)bufH;
  short* g2 = (short*)bufH;   // aliases g1 (g1 dead when g2 written)

  k_prepW     <<<32, 256, 0, stream>>>(W1, W2, Wt1, Wt2);
  k_hist      <<<NCHNK, 256, 0, stream>>>(col, E, NBUCK, chist);
  k_scanbuck  <<<NBUCK, 256, 0, stream>>>(chist, NCHNK, NBUCK, btot);
  k_scanbase  <<<1, 512, 0, stream>>>(btot, NBUCK, bbase, row_start, N);
  k_binpass   <<<NCHNK, 256, 0, stream>>>(row, col, E, NBUCK, bbase, chist, adjTmp);
  k_bucketsort<<<NBUCK, 256, 0, stream>>>(bbase, adjTmp, adj, row_start, dinv, N);

  k_gemm1<<<(N + 63) / 64, 256, 0, stream>>>(x, Wt1, dinv, g1, N);
  k_gagg1<<<(N + 3) / 4, 256, 0, stream>>>(row_start, adj, dinv, (const short*)g1, b1, z1b, N);

  k_gemm2<<<(N + 63) / 64, 256, 0, stream>>>((const bf16*)z1b, Wt2, dinv, g2, N);
  k_gagg2<<<(N + 3) / 4, 256, 0, stream>>>(row_start, adj, dinv, g2, b2, z2, N);

  k_decode<<<(EL + 7) / 8, 256, 0, stream>>>(eli, eli + EL, z2, (float*)d_out, EL);
}

// Round 4
// 306.633 us; speedup vs baseline: 6.5692x; 1.0137x over previous
//
#include <hip/hip_runtime.h>
#include <hip/hip_bf16.h>

typedef __hip_bfloat16 bf16;
typedef short s8v __attribute__((ext_vector_type(8)));   // 8 bf16 in 4 VGPRs
typedef float f4v __attribute__((ext_vector_type(4)));   // MFMA 16x16 C/D frag
typedef float v2f __attribute__((ext_vector_type(2)));   // packed f32 pair (v_pk_add_f32)

__device__ __forceinline__ short f2b(float f) {
  bf16 h = __float2bfloat16(f);
  return *reinterpret_cast<short*>(&h);
}
// accumulate 2 bf16 (one dword, memory order) into packed f32 pair
__device__ __forceinline__ void bf2_acc(int d, v2f& a) {
  v2f u;
  u.x = __int_as_float(d << 16);
  u.y = __int_as_float(d & 0xFFFF0000);
  a += u;   // single v_pk_add_f32
}

#define BSHIFT 8        // 256 dest nodes per bucket
#define BNODES 256
#define CHUNK 4096      // edges per chunk
#define SORT_CAP 12288  // bucket-sort LDS capacity (48 KB); mean bucket = 8192
#define TSHIFT 15       // source tile = 32K rows = 4 MB of g1 (fits per-XCD L2)

// ---- phase 1: per-chunk bucket histogram (LDS atomics only) ----
__global__ __launch_bounds__(256) void k_hist(const int* __restrict__ col, int E,
                                              int nbuck, int* __restrict__ chist) {
  __shared__ int hist[512];
  int t = threadIdx.x;
  hist[t] = 0; hist[t + 256] = 0;
  __syncthreads();
  int e0 = blockIdx.x * CHUNK;
#pragma unroll
  for (int i = 0; i < 16; i++) {
    int e = e0 + i * 256 + t;
    if (e < E) atomicAdd(&hist[col[e] >> BSHIFT], 1);
  }
  __syncthreads();
  int* out = chist + (size_t)blockIdx.x * nbuck;
  for (int b = t; b < nbuck; b += 256) out[b] = hist[b];  // coalesced
}

// ---- phase 2: per-bucket exclusive scan over chunks (in place) ----
__global__ __launch_bounds__(256) void k_scanbuck(int* __restrict__ chist, int nchnk,
                                                  int nbuck, int* __restrict__ btot) {
  __shared__ int sm[256];
  int b = blockIdx.x, t = threadIdx.x;
  int per = (nchnk + 255) / 256;
  int lo = t * per, hi = min(lo + per, nchnk);
  int s = 0;
  for (int i = lo; i < hi; i++) s += chist[(size_t)i * nbuck + b];
  sm[t] = s;
  __syncthreads();
  for (int d = 1; d < 256; d <<= 1) {
    int x = (t >= d) ? sm[t - d] : 0;
    __syncthreads();
    sm[t] += x;
    __syncthreads();
  }
  int off = (t == 0) ? 0 : sm[t - 1];
  for (int i = lo; i < hi; i++) {
    int c = chist[(size_t)i * nbuck + b];
    chist[(size_t)i * nbuck + b] = off;
    off += c;
  }
  if (t == 255) btot[b] = sm[255];
}

// ---- phase 3: scan bucket totals (parallel LDS scan) ----
__global__ __launch_bounds__(512) void k_scanbase(const int* __restrict__ btot, int nbuck,
                                                  int* __restrict__ bbase,
                                                  int* __restrict__ row_start, int n) {
  __shared__ int sm[512];
  int t = threadIdx.x;
  int v = (t < nbuck) ? btot[t] : 0;
  sm[t] = v;
  __syncthreads();
  for (int d = 1; d < 512; d <<= 1) {   // Hillis-Steele inclusive
    int x = (t >= d) ? sm[t - d] : 0;
    __syncthreads();
    sm[t] += x;
    __syncthreads();
  }
  if (t < nbuck) bbase[t] = sm[t] - v;  // exclusive prefix
  if (t == nbuck - 1) {
    bbase[nbuck] = sm[t];
    row_start[n] = sm[t];  // == E
  }
}

// ---- phase 4: grouped scatter into bucket-sorted adjTmp, NO global atomics ----
// adjTmp entry: r | (c_low << 17)
__global__ __launch_bounds__(256) void k_binpass(const int* __restrict__ row,
                                                 const int* __restrict__ col, int E,
                                                 int nbuck,
                                                 const int* __restrict__ bbase,
                                                 const int* __restrict__ chist,
                                                 int* __restrict__ adjTmp) {
  __shared__ int hist[512];
  __shared__ int base[512];
  __shared__ int lcur[512];
  __shared__ int gbase[512];
  __shared__ int psum[256];
  __shared__ int stage[CHUNK];
  __shared__ unsigned short sbkt[CHUNK];
  __shared__ int s_total;
  int t = threadIdx.x;
  int e0 = blockIdx.x * CHUNK;

  hist[t] = 0; hist[t + 256] = 0;
  __syncthreads();

  int pk[16], bk[16];
#pragma unroll
  for (int i = 0; i < 16; i++) {
    int e = e0 + i * 256 + t;
    if (e < E) {
      int c = col[e];
      int r = row[e];
      bk[i] = c >> BSHIFT;
      pk[i] = r | ((c & (BNODES - 1)) << 17);
      atomicAdd(&hist[bk[i]], 1);
    } else bk[i] = -1;
  }
  __syncthreads();
  int a0 = hist[2 * t], a1 = hist[2 * t + 1];
  psum[t] = a0 + a1;
  __syncthreads();
  for (int d = 1; d < 256; d <<= 1) {
    int v = (t >= d) ? psum[t - d] : 0;
    __syncthreads();
    psum[t] += v;
    __syncthreads();
  }
  int pref = (t == 0) ? 0 : psum[t - 1];
  base[2 * t] = pref;          lcur[2 * t] = pref;
  base[2 * t + 1] = pref + a0; lcur[2 * t + 1] = pref + a0;
  if (t == 255) s_total = psum[255];
  const int* coff = chist + (size_t)blockIdx.x * nbuck;
  for (int b = t; b < nbuck; b += 256) gbase[b] = bbase[b] + coff[b];
  __syncthreads();
#pragma unroll
  for (int i = 0; i < 16; i++) {
    if (bk[i] >= 0) {
      int pos = atomicAdd(&lcur[bk[i]], 1);
      stage[pos] = pk[i];
      sbkt[pos] = (unsigned short)bk[i];
    }
  }
  __syncthreads();
  int total = s_total;
  for (int i = t; i < total; i += 256) {
    int b = sbkt[i];
    adjTmp[gbase[b] + (i - base[b])] = stage[i];
  }
}

// ---- phase 5: per-bucket sort, key = (c_low, src_tile); emits dinv, row_start,
//      adj sorted by dest node; adj entries premultiplied: r << 7 (byte offset
//      of the 128 B g1 row; gagg2 shifts right by 1 for its 64 B rows) ----
__global__ __launch_bounds__(256) void k_bucketsort(const int* __restrict__ bbase,
                                                    const int* __restrict__ adjTmp,
                                                    int* __restrict__ adj,
                                                    int* __restrict__ row_start,
                                                    float* __restrict__ dinv, int n) {
  __shared__ int cnt[1024];
  __shared__ int sc[256];
  __shared__ int cur[1024];
  __shared__ int stage[SORT_CAP];
  int b = blockIdx.x, t = threadIdx.x;
  int node_base = b << BSHIFT;
  int nnode = min(BNODES, n - node_base);
  int seg_base = bbase[b];
  int cntE = bbase[b + 1] - seg_base;
  cnt[t] = 0; cnt[t + 256] = 0; cnt[t + 512] = 0; cnt[t + 768] = 0;
  __syncthreads();
  for (int i = t; i < cntE; i += 256) {
    int p = adjTmp[seg_base + i];
    int key = (((p >> 17) & 255) << 2) | ((p >> TSHIFT) & 3);
    atomicAdd(&cnt[key], 1);
  }
  __syncthreads();
  int c0 = cnt[4 * t], c1 = cnt[4 * t + 1], c2 = cnt[4 * t + 2], c3 = cnt[4 * t + 3];
  int myc = c0 + c1 + c2 + c3;        // node degree
  sc[t] = myc;
  __syncthreads();
  for (int d = 1; d < 256; d <<= 1) {
    int x = (t >= d) ? sc[t - d] : 0;
    __syncthreads();
    sc[t] += x;
    __syncthreads();
  }
  int excl = (t == 0) ? 0 : sc[t - 1];
  cur[4 * t] = excl;
  cur[4 * t + 1] = excl + c0;
  cur[4 * t + 2] = excl + c0 + c1;
  cur[4 * t + 3] = excl + c0 + c1 + c2;
  if (t < nnode) {
    row_start[node_base + t] = seg_base + excl;
    dinv[node_base + t] = rsqrtf((float)myc + 1.0f);  // +1 = self-loop
  }
  __syncthreads();
  if (cntE <= SORT_CAP) {
    for (int i = t; i < cntE; i += 256) {
      int p = adjTmp[seg_base + i];
      int key = (((p >> 17) & 255) << 2) | ((p >> TSHIFT) & 3);
      int pos = atomicAdd(&cur[key], 1);
      stage[pos] = (p & 0x1FFFF) << 7;
    }
    __syncthreads();
    for (int i = t; i < cntE; i += 256) adj[seg_base + i] = stage[i];
  } else {
    // fallback (statistically never)
    for (int i = t; i < cntE; i += 256) {
      int p = adjTmp[seg_base + i];
      int key = (((p >> 17) & 255) << 2) | ((p >> TSHIFT) & 3);
      int pos = atomicAdd(&cur[key], 1);
      adj[seg_base + pos] = (p & 0x1FFFF) << 7;
    }
  }
}

// ---- weight prep: Wt1[64][128] = W1^T bf16, Wt2[32][64] = W2^T bf16 ----
__global__ __launch_bounds__(256) void k_prepW(const float* __restrict__ W1,
                                               const float* __restrict__ W2,
                                               short* __restrict__ Wt1,
                                               short* __restrict__ Wt2) {
  int t = blockIdx.x * 256 + threadIdx.x;
  if (t < 128 * 64) { int k = t >> 6, c = t & 63; Wt1[c * 128 + k] = f2b(W1[t]); }
  if (t < 64 * 32)  { int k = t >> 5, c = t & 31; Wt2[c * 64 + k] = f2b(W2[t]); }
}

// ---- MFMA gemm1: g1[n,64] = dinv[r]*(x[n,128] @ W1[128,64]), bf16 out ----
__global__ __launch_bounds__(256) void k_gemm1(const float* __restrict__ x,
                                               const short* __restrict__ Wt,  // [64][128] bf16
                                               const float* __restrict__ dinv,
                                               bf16* __restrict__ g1, int n) {
  int wave = threadIdx.x >> 6;
  int lane = threadIdx.x & 63;
  int m = lane & 15;
  int quad = lane >> 4;
  int r = blockIdx.x * 64 + wave * 16 + m;

  s8v afr[4];
  if (r < n) {
    const float* ap = x + (size_t)r * 128 + quad * 8;
#pragma unroll
    for (int kc = 0; kc < 4; kc++) {
      float4 u = *(const float4*)(ap + kc * 32);
      float4 v = *(const float4*)(ap + kc * 32 + 4);
      s8v a;
      a[0] = f2b(u.x); a[1] = f2b(u.y); a[2] = f2b(u.z); a[3] = f2b(u.w);
      a[4] = f2b(v.x); a[5] = f2b(v.y); a[6] = f2b(v.z); a[7] = f2b(v.w);
      afr[kc] = a;
    }
  } else {
#pragma unroll
    for (int kc = 0; kc < 4; kc++) afr[kc] = (s8v)(short)0;
  }

  const short* wp = Wt + (size_t)m * 128 + quad * 8;
  s8v bfr[4][4];
#pragma unroll
  for (int nt = 0; nt < 4; nt++)
#pragma unroll
    for (int kc = 0; kc < 4; kc++)
      bfr[nt][kc] = *(const s8v*)(wp + nt * 16 * 128 + kc * 32);

  f4v acc[4] = {f4v{0,0,0,0}, f4v{0,0,0,0}, f4v{0,0,0,0}, f4v{0,0,0,0}};
#pragma unroll
  for (int kc = 0; kc < 4; kc++)
#pragma unroll
    for (int nt = 0; nt < 4; nt++)
      acc[nt] = __builtin_amdgcn_mfma_f32_16x16x32_bf16(afr[kc], bfr[nt][kc], acc[nt], 0, 0, 0);

  int rbase = blockIdx.x * 64 + wave * 16 + quad * 4;
#pragma unroll
  for (int reg = 0; reg < 4; reg++) {
    int rr = rbase + reg;
    if (rr < n) {
      float dv = dinv[rr];
#pragma unroll
      for (int nt = 0; nt < 4; nt++)
        g1[(size_t)rr * 64 + nt * 16 + m] = __float2bfloat16(acc[nt][reg] * dv);
    }
  }
}

// ---- MFMA gemm2: g2[n,32] = dinv[r]*(z1b[n,64] @ W2[64,32]), bf16 out ----
__global__ __launch_bounds__(256) void k_gemm2(const bf16* __restrict__ z1b,
                                               const short* __restrict__ Wt,  // [32][64] bf16
                                               const float* __restrict__ dinv,
                                               short* __restrict__ g2, int n) {
  int wave = threadIdx.x >> 6;
  int lane = threadIdx.x & 63;
  int m = lane & 15;
  int quad = lane >> 4;
  int r = blockIdx.x * 64 + wave * 16 + m;

  s8v afr[2];
  if (r < n) {
    const short* ap = (const short*)z1b + (size_t)r * 64 + quad * 8;
#pragma unroll
    for (int kc = 0; kc < 2; kc++) afr[kc] = *(const s8v*)(ap + kc * 32);
  } else {
#pragma unroll
    for (int kc = 0; kc < 2; kc++) afr[kc] = (s8v)(short)0;
  }

  const short* wp = Wt + (size_t)m * 64 + quad * 8;
  s8v bfr[2][2];
#pragma unroll
  for (int nt = 0; nt < 2; nt++)
#pragma unroll
    for (int kc = 0; kc < 2; kc++)
      bfr[nt][kc] = *(const s8v*)(wp + nt * 16 * 64 + kc * 32);

  f4v acc[2] = {f4v{0,0,0,0}, f4v{0,0,0,0}};
#pragma unroll
  for (int kc = 0; kc < 2; kc++)
#pragma unroll
    for (int nt = 0; nt < 2; nt++)
      acc[nt] = __builtin_amdgcn_mfma_f32_16x16x32_bf16(afr[kc], bfr[nt][kc], acc[nt], 0, 0, 0);

  int rbase = blockIdx.x * 64 + wave * 16 + quad * 4;
#pragma unroll
  for (int reg = 0; reg < 4; reg++) {
    int rr = rbase + reg;
    if (rr < n) {
      float dv = dinv[rr];
#pragma unroll
      for (int nt = 0; nt < 2; nt++)
        g2[(size_t)rr * 32 + nt * 16 + m] = f2b(acc[nt][reg] * dv);
    }
  }
}

// ---- layer-1 aggregate: 1 wave/dest, 8 lanes x 16B per edge (8 edges/inst) ----
// round-0 structure; r13: premultiplied adj offsets (saddr-form gathers) +
// packed v_pk_add_f32 accumulate. Per-feature add order identical to round-0.
__global__ __launch_bounds__(256) void k_gagg1(const int* __restrict__ row_start,
                                               const int* __restrict__ adj,
                                               const float* __restrict__ dinv,
                                               const short* __restrict__ g,   // g1 bf16 [n][64]
                                               const float* __restrict__ bias,
                                               short* __restrict__ z, int n) {
  int wave = threadIdx.x >> 6;
  int lane = threadIdx.x & 63;
  int grp = lane >> 3;     // 0..7: edge slot
  int fl = lane & 7;       // feature slice: shorts fl*8..fl*8+7 (16 B)
  int c = blockIdx.x * 4 + wave;
  if (c >= n) return;
  int start = row_start[c], end = row_start[c + 1];
  const char* gb = (const char*)g;
  int fo = fl * 16;        // byte offset of feature slice within a 128 B row
  v2f a0 = {0.f,0.f}, a1 = {0.f,0.f}, a2 = {0.f,0.f}, a3 = {0.f,0.f};
  int j = start;
  for (; j + 32 <= end; j += 32) {      // 32 edges (4 KB) in flight per iter
#pragma unroll
    for (int u = 0; u < 4; u++) {
      int voff = adj[j + u * 8 + grp];  // = r << 7
      int4 pk = *(const int4*)(gb + (unsigned)(voff + fo));
      bf2_acc(pk.x, a0); bf2_acc(pk.y, a1);
      bf2_acc(pk.z, a2); bf2_acc(pk.w, a3);
    }
  }
  for (; j < end; j += 8) {
    int e = j + grp;
    if (e < end) {
      int voff = adj[e];
      int4 pk = *(const int4*)(gb + (unsigned)(voff + fo));
      bf2_acc(pk.x, a0); bf2_acc(pk.y, a1);
      bf2_acc(pk.z, a2); bf2_acc(pk.w, a3);
    }
  }
  // reduce 8 edge slots (lane bits 3..5)
#pragma unroll
  for (int s = 8; s <= 32; s <<= 1) {
    a0.x += __shfl_xor(a0.x, s); a0.y += __shfl_xor(a0.y, s);
    a1.x += __shfl_xor(a1.x, s); a1.y += __shfl_xor(a1.y, s);
    a2.x += __shfl_xor(a2.x, s); a2.y += __shfl_xor(a2.y, s);
    a3.x += __shfl_xor(a3.x, s); a3.y += __shfl_xor(a3.y, s);
  }
  if (grp == 0) {
    int4 pk = *(const int4*)(gb + (((unsigned)c << 7) + fo));   // self-loop
    bf2_acc(pk.x, a0); bf2_acc(pk.y, a1);
    bf2_acc(pk.z, a2); bf2_acc(pk.w, a3);
    float d = dinv[c];
    float4 b0 = *(const float4*)(bias + fl * 8);
    float4 b1 = *(const float4*)(bias + fl * 8 + 4);
    float v0 = fmaxf(fmaf(d, a0.x, b0.x), 0.f);
    float v1 = fmaxf(fmaf(d, a0.y, b0.y), 0.f);
    float v2 = fmaxf(fmaf(d, a1.x, b0.z), 0.f);
    float v3 = fmaxf(fmaf(d, a1.y, b0.w), 0.f);
    float v4 = fmaxf(fmaf(d, a2.x, b1.x), 0.f);
    float v5 = fmaxf(fmaf(d, a2.y, b1.y), 0.f);
    float v6 = fmaxf(fmaf(d, a3.x, b1.z), 0.f);
    float v7 = fmaxf(fmaf(d, a3.y, b1.w), 0.f);
    int4 out;
    out.x = (int)(unsigned short)f2b(v0) | ((int)f2b(v1) << 16);
    out.y = (int)(unsigned short)f2b(v2) | ((int)f2b(v3) << 16);
    out.z = (int)(unsigned short)f2b(v4) | ((int)f2b(v5) << 16);
    out.w = (int)(unsigned short)f2b(v6) | ((int)f2b(v7) << 16);
    *(int4*)(z + c * 64 + fl * 8) = out;
  }
}

// ---- layer-2 aggregate: 1 wave/dest, 4 lanes x 16B per edge (16 edges/inst) ----
// round-0 structure; r13 treatment (adj>>1 gives the 64 B row byte offset).
__global__ __launch_bounds__(256) void k_gagg2(const int* __restrict__ row_start,
                                               const int* __restrict__ adj,
                                               const float* __restrict__ dinv,
                                               const short* __restrict__ g,   // g2 bf16 [n][32]
                                               const float* __restrict__ bias,
                                               float* __restrict__ z, int n) {
  int wave = threadIdx.x >> 6;
  int lane = threadIdx.x & 63;
  int grp = lane >> 2;     // 0..15: edge slot
  int fl = lane & 3;       // feature slice: shorts fl*8..fl*8+7 (16 B)
  int c = blockIdx.x * 4 + wave;
  if (c >= n) return;
  int start = row_start[c], end = row_start[c + 1];
  const char* gb = (const char*)g;
  int fo = fl * 16;        // byte offset within a 64 B row
  v2f a0 = {0.f,0.f}, a1 = {0.f,0.f}, a2 = {0.f,0.f}, a3 = {0.f,0.f};
  int j = start;
  for (; j + 32 <= end; j += 32) {      // 32 edges (2 KB) in flight per iter
#pragma unroll
    for (int u = 0; u < 2; u++) {
      int voff = adj[j + u * 16 + grp] >> 1;   // r << 6
      int4 pk = *(const int4*)(gb + (unsigned)(voff + fo));
      bf2_acc(pk.x, a0); bf2_acc(pk.y, a1);
      bf2_acc(pk.z, a2); bf2_acc(pk.w, a3);
    }
  }
  for (; j < end; j += 16) {
    int e = j + grp;
    if (e < end) {
      int voff = adj[e] >> 1;
      int4 pk = *(const int4*)(gb + (unsigned)(voff + fo));
      bf2_acc(pk.x, a0); bf2_acc(pk.y, a1);
      bf2_acc(pk.z, a2); bf2_acc(pk.w, a3);
    }
  }
  // reduce 16 edge slots (lane bits 2..5)
#pragma unroll
  for (int s = 4; s <= 32; s <<= 1) {
    a0.x += __shfl_xor(a0.x, s); a0.y += __shfl_xor(a0.y, s);
    a1.x += __shfl_xor(a1.x, s); a1.y += __shfl_xor(a1.y, s);
    a2.x += __shfl_xor(a2.x, s); a2.y += __shfl_xor(a2.y, s);
    a3.x += __shfl_xor(a3.x, s); a3.y += __shfl_xor(a3.y, s);
  }
  if (grp == 0) {
    int4 pk = *(const int4*)(gb + (((unsigned)c << 6) + fo));   // self-loop
    bf2_acc(pk.x, a0); bf2_acc(pk.y, a1);
    bf2_acc(pk.z, a2); bf2_acc(pk.w, a3);
    float d = dinv[c];
    float4 b0 = *(const float4*)(bias + fl * 8);
    float4 b1 = *(const float4*)(bias + fl * 8 + 4);
    float4 o0, o1;
    o0.x = fmaf(d, a0.x, b0.x); o0.y = fmaf(d, a0.y, b0.y);
    o0.z = fmaf(d, a1.x, b0.z); o0.w = fmaf(d, a1.y, b0.w);
    o1.x = fmaf(d, a2.x, b1.x); o1.y = fmaf(d, a2.y, b1.y);
    o1.z = fmaf(d, a3.x, b1.z); o1.w = fmaf(d, a3.y, b1.w);
    *(float4*)(z + c * 32 + fl * 8) = o0;
    *(float4*)(z + c * 32 + fl * 8 + 4) = o1;
  }
}

// ---- link decode: half-wave per label edge, shuffle reduce, fp32 out ----
__global__ __launch_bounds__(256) void k_decode(const int* __restrict__ ea,
                                                const int* __restrict__ eb,
                                                const float* __restrict__ z2,
                                                float* __restrict__ out, int EL) {
  int lane = threadIdx.x & 31;
  int e = blockIdx.x * 8 + (threadIdx.x >> 5);
  if (e >= EL) return;
  int a = ea[e], b = eb[e];
  float p = z2[a * 32 + lane] * z2[b * 32 + lane];
  p += __shfl_down(p, 16);
  p += __shfl_down(p, 8);
  p += __shfl_down(p, 4);
  p += __shfl_down(p, 2);
  p += __shfl_down(p, 1);
  if (lane == 0) out[e] = p;
}

extern "C" void kernel_launch(void* const* d_in, const int* in_sizes, int n_in,
                              void* d_out, int out_size, void* d_ws, size_t ws_size,
                              hipStream_t stream) {
  const float* x   = (const float*)d_in[0];
  const float* W1  = (const float*)d_in[1];
  const float* b1  = (const float*)d_in[2];
  const float* W2  = (const float*)d_in[3];
  const float* b2  = (const float*)d_in[4];
  const int*   ei  = (const int*)d_in[5];   // [2,E]: row=ei[0..E), col=ei[E..2E)
  const int*   eli = (const int*)d_in[6];   // [2,EL]

  const int N  = in_sizes[0] / 128;  // 100000
  const int E  = in_sizes[5] / 2;    // 3200000
  const int EL = in_sizes[6] / 2;    // 200000
  const int* row = ei;
  const int* col = ei + E;
  const int NBUCK = (N + BNODES - 1) / BNODES;   // 391
  const int NCHNK = (E + CHUNK - 1) / CHUNK;     // 782

  // workspace (~60 MB)
  char* ws = (char*)d_ws;
  size_t off = 0;
  auto take = [&](size_t bytes) { char* p = ws + off; off += (bytes + 255) & ~(size_t)255; return p; };
  float* dinv      = (float*)take((size_t)N * 4);
  int*   row_start = (int*)take((size_t)(N + 1) * 4);
  int*   btot      = (int*)take((size_t)NBUCK * 4);
  int*   bbase     = (int*)take((size_t)(NBUCK + 1) * 4);
  short* Wt1       = (short*)take((size_t)64 * 128 * 2);
  short* Wt2       = (short*)take((size_t)32 * 64 * 2);
  int*   chist     = (int*)take((size_t)NCHNK * NBUCK * 4);   // 1.22 MB
  int*   adjTmp    = (int*)take((size_t)E * 4);               // 12.8 MB
  int*   adj       = (int*)take((size_t)E * 4);               // 12.8 MB
  char*  bufH      = take((size_t)N * 64 * 2);                // g1 bf16 / g2 bf16
  short* z1b       = (short*)take((size_t)N * 64 * 2);        // relu'd, bf16
  float* z2        = (float*)take((size_t)N * 32 * 4);
  (void)ws_size; (void)n_in; (void)out_size;

  bf16*  g1 = (bf16*)bufH;
  short* g2 = (short*)bufH;   // aliases g1 (g1 dead when g2 written)

  k_prepW     <<<32, 256, 0, stream>>>(W1, W2, Wt1, Wt2);
  k_hist      <<<NCHNK, 256, 0, stream>>>(col, E, NBUCK, chist);
  k_scanbuck  <<<NBUCK, 256, 0, stream>>>(chist, NCHNK, NBUCK, btot);
  k_scanbase  <<<1, 512, 0, stream>>>(btot, NBUCK, bbase, row_start, N);
  k_binpass   <<<NCHNK, 256, 0, stream>>>(row, col, E, NBUCK, bbase, chist, adjTmp);
  k_bucketsort<<<NBUCK, 256, 0, stream>>>(bbase, adjTmp, adj, row_start, dinv, N);

  k_gemm1<<<(N + 63) / 64, 256, 0, stream>>>(x, Wt1, dinv, g1, N);
  k_gagg1<<<(N + 3) / 4, 256, 0, stream>>>(row_start, adj, dinv, (const short*)g1, b1, z1b, N);

  k_gemm2<<<(N + 63) / 64, 256, 0, stream>>>((const bf16*)z1b, Wt2, dinv, g2, N);
  k_gagg2<<<(N + 3) / 4, 256, 0, stream>>>(row_start, adj, dinv, g2, b2, z2, N);

  k_decode<<<(EL + 7) / 8, 256, 0, stream>>>(eli, eli + EL, z2, (float*)d_out, EL);
}

// Round 6
// 303.145 us; speedup vs baseline: 6.6448x; 1.0115x over previous
//
#include <hip/hip_runtime.h>
#include <hip/hip_bf16.h>

typedef __hip_bfloat16 bf16;
typedef short s8v __attribute__((ext_vector_type(8)));   // 8 bf16 in 4 VGPRs
typedef float f4v __attribute__((ext_vector_type(4)));   // MFMA 16x16 C/D frag
typedef float v2f __attribute__((ext_vector_type(2)));   // packed f32 pair (v_pk_add_f32)

__device__ __forceinline__ short f2b(float f) {
  bf16 h = __float2bfloat16(f);
  return *reinterpret_cast<short*>(&h);
}
// accumulate 2 bf16 (one dword, memory order) into packed f32 pair
__device__ __forceinline__ void bf2_acc(int d, v2f& a) {
  v2f u;
  u.x = __int_as_float(d << 16);
  u.y = __int_as_float(d & 0xFFFF0000);
  a += u;   // single v_pk_add_f32
}

#define BSHIFT 8        // 256 dest nodes per bucket
#define BNODES 256
#define CHUNK 4096      // edges per chunk
#define SORT_CAP 12288  // bucket-sort LDS capacity (48 KB); mean bucket = 8192
#define TSHIFT 15       // source tile = 32K rows = 4 MB of g1 (fits per-XCD L2)

// ---- phase 1: per-chunk bucket histogram (LDS atomics only) ----
__global__ __launch_bounds__(256) void k_hist(const int* __restrict__ col, int E,
                                              int nbuck, int* __restrict__ chist) {
  __shared__ int hist[512];
  int t = threadIdx.x;
  hist[t] = 0; hist[t + 256] = 0;
  __syncthreads();
  int e0 = blockIdx.x * CHUNK;
#pragma unroll
  for (int i = 0; i < 16; i++) {
    int e = e0 + i * 256 + t;
    if (e < E) atomicAdd(&hist[col[e] >> BSHIFT], 1);
  }
  __syncthreads();
  int* out = chist + (size_t)blockIdx.x * nbuck;
  for (int b = t; b < nbuck; b += 256) out[b] = hist[b];  // coalesced
}

// ---- phase 2: per-bucket exclusive scan over chunks (in place) ----
__global__ __launch_bounds__(256) void k_scanbuck(int* __restrict__ chist, int nchnk,
                                                  int nbuck, int* __restrict__ btot) {
  __shared__ int sm[256];
  int b = blockIdx.x, t = threadIdx.x;
  int per = (nchnk + 255) / 256;
  int lo = t * per, hi = min(lo + per, nchnk);
  int s = 0;
  for (int i = lo; i < hi; i++) s += chist[(size_t)i * nbuck + b];
  sm[t] = s;
  __syncthreads();
  for (int d = 1; d < 256; d <<= 1) {
    int x = (t >= d) ? sm[t - d] : 0;
    __syncthreads();
    sm[t] += x;
    __syncthreads();
  }
  int off = (t == 0) ? 0 : sm[t - 1];
  for (int i = lo; i < hi; i++) {
    int c = chist[(size_t)i * nbuck + b];
    chist[(size_t)i * nbuck + b] = off;
    off += c;
  }
  if (t == 255) btot[b] = sm[255];
}

// ---- phase 3: scan bucket totals (parallel LDS scan) ----
__global__ __launch_bounds__(512) void k_scanbase(const int* __restrict__ btot, int nbuck,
                                                  int* __restrict__ bbase,
                                                  int* __restrict__ row_start, int n) {
  __shared__ int sm[512];
  int t = threadIdx.x;
  int v = (t < nbuck) ? btot[t] : 0;
  sm[t] = v;
  __syncthreads();
  for (int d = 1; d < 512; d <<= 1) {   // Hillis-Steele inclusive
    int x = (t >= d) ? sm[t - d] : 0;
    __syncthreads();
    sm[t] += x;
    __syncthreads();
  }
  if (t < nbuck) bbase[t] = sm[t] - v;  // exclusive prefix
  if (t == nbuck - 1) {
    bbase[nbuck] = sm[t];
    row_start[n] = sm[t];  // == E
  }
}

// ---- phase 4: grouped scatter into bucket-sorted adjTmp, NO global atomics ----
// adjTmp entry: r | (c_low << 17)
__global__ __launch_bounds__(256) void k_binpass(const int* __restrict__ row,
                                                 const int* __restrict__ col, int E,
                                                 int nbuck,
                                                 const int* __restrict__ bbase,
                                                 const int* __restrict__ chist,
                                                 int* __restrict__ adjTmp) {
  __shared__ int hist[512];
  __shared__ int base[512];
  __shared__ int lcur[512];
  __shared__ int gbase[512];
  __shared__ int psum[256];
  __shared__ int stage[CHUNK];
  __shared__ unsigned short sbkt[CHUNK];
  __shared__ int s_total;
  int t = threadIdx.x;
  int e0 = blockIdx.x * CHUNK;

  hist[t] = 0; hist[t + 256] = 0;
  __syncthreads();

  int pk[16], bk[16];
#pragma unroll
  for (int i = 0; i < 16; i++) {
    int e = e0 + i * 256 + t;
    if (e < E) {
      int c = col[e];
      int r = row[e];
      bk[i] = c >> BSHIFT;
      pk[i] = r | ((c & (BNODES - 1)) << 17);
      atomicAdd(&hist[bk[i]], 1);
    } else bk[i] = -1;
  }
  __syncthreads();
  int a0 = hist[2 * t], a1 = hist[2 * t + 1];
  psum[t] = a0 + a1;
  __syncthreads();
  for (int d = 1; d < 256; d <<= 1) {
    int v = (t >= d) ? psum[t - d] : 0;
    __syncthreads();
    psum[t] += v;
    __syncthreads();
  }
  int pref = (t == 0) ? 0 : psum[t - 1];
  base[2 * t] = pref;          lcur[2 * t] = pref;
  base[2 * t + 1] = pref + a0; lcur[2 * t + 1] = pref + a0;
  if (t == 255) s_total = psum[255];
  const int* coff = chist + (size_t)blockIdx.x * nbuck;
  for (int b = t; b < nbuck; b += 256) gbase[b] = bbase[b] + coff[b];
  __syncthreads();
#pragma unroll
  for (int i = 0; i < 16; i++) {
    if (bk[i] >= 0) {
      int pos = atomicAdd(&lcur[bk[i]], 1);
      stage[pos] = pk[i];
      sbkt[pos] = (unsigned short)bk[i];
    }
  }
  __syncthreads();
  int total = s_total;
  for (int i = t; i < total; i += 256) {
    int b = sbkt[i];
    adjTmp[gbase[b] + (i - base[b])] = stage[i];
  }
}

// ---- phase 5: per-bucket sort, key = (c_low, src_tile); emits dinv, row_start,
//      adj sorted by dest node; adj entries premultiplied: r << 7 (byte offset
//      of the 128 B g1 row; gagg2 shifts right by 1 for its 64 B rows) ----
__global__ __launch_bounds__(256) void k_bucketsort(const int* __restrict__ bbase,
                                                    const int* __restrict__ adjTmp,
                                                    int* __restrict__ adj,
                                                    int* __restrict__ row_start,
                                                    float* __restrict__ dinv, int n) {
  __shared__ int cnt[1024];
  __shared__ int sc[256];
  __shared__ int cur[1024];
  __shared__ int stage[SORT_CAP];
  int b = blockIdx.x, t = threadIdx.x;
  int node_base = b << BSHIFT;
  int nnode = min(BNODES, n - node_base);
  int seg_base = bbase[b];
  int cntE = bbase[b + 1] - seg_base;
  cnt[t] = 0; cnt[t + 256] = 0; cnt[t + 512] = 0; cnt[t + 768] = 0;
  __syncthreads();
  for (int i = t; i < cntE; i += 256) {
    int p = adjTmp[seg_base + i];
    int key = (((p >> 17) & 255) << 2) | ((p >> TSHIFT) & 3);
    atomicAdd(&cnt[key], 1);
  }
  __syncthreads();
  int c0 = cnt[4 * t], c1 = cnt[4 * t + 1], c2 = cnt[4 * t + 2], c3 = cnt[4 * t + 3];
  int myc = c0 + c1 + c2 + c3;        // node degree
  sc[t] = myc;
  __syncthreads();
  for (int d = 1; d < 256; d <<= 1) {
    int x = (t >= d) ? sc[t - d] : 0;
    __syncthreads();
    sc[t] += x;
    __syncthreads();
  }
  int excl = (t == 0) ? 0 : sc[t - 1];
  cur[4 * t] = excl;
  cur[4 * t + 1] = excl + c0;
  cur[4 * t + 2] = excl + c0 + c1;
  cur[4 * t + 3] = excl + c0 + c1 + c2;
  if (t < nnode) {
    row_start[node_base + t] = seg_base + excl;
    dinv[node_base + t] = rsqrtf((float)myc + 1.0f);  // +1 = self-loop
  }
  __syncthreads();
  if (cntE <= SORT_CAP) {
    for (int i = t; i < cntE; i += 256) {
      int p = adjTmp[seg_base + i];
      int key = (((p >> 17) & 255) << 2) | ((p >> TSHIFT) & 3);
      int pos = atomicAdd(&cur[key], 1);
      stage[pos] = (p & 0x1FFFF) << 7;
    }
    __syncthreads();
    for (int i = t; i < cntE; i += 256) adj[seg_base + i] = stage[i];
  } else {
    // fallback (statistically never)
    for (int i = t; i < cntE; i += 256) {
      int p = adjTmp[seg_base + i];
      int key = (((p >> 17) & 255) << 2) | ((p >> TSHIFT) & 3);
      int pos = atomicAdd(&cur[key], 1);
      adj[seg_base + pos] = (p & 0x1FFFF) << 7;
    }
  }
}

// ---- weight prep: Wt1[64][128] = W1^T bf16, Wt2[32][64] = W2^T bf16 ----
__global__ __launch_bounds__(256) void k_prepW(const float* __restrict__ W1,
                                               const float* __restrict__ W2,
                                               short* __restrict__ Wt1,
                                               short* __restrict__ Wt2) {
  int t = blockIdx.x * 256 + threadIdx.x;
  if (t < 128 * 64) { int k = t >> 6, c = t & 63; Wt1[c * 128 + k] = f2b(W1[t]); }
  if (t < 64 * 32)  { int k = t >> 5, c = t & 31; Wt2[c * 64 + k] = f2b(W2[t]); }
}

// ---- MFMA gemm1: g1[n,64] = dinv[r]*(x[n,128] @ W1[128,64]), bf16 out ----
__global__ __launch_bounds__(256) void k_gemm1(const float* __restrict__ x,
                                               const short* __restrict__ Wt,  // [64][128] bf16
                                               const float* __restrict__ dinv,
                                               bf16* __restrict__ g1, int n) {
  int wave = threadIdx.x >> 6;
  int lane = threadIdx.x & 63;
  int m = lane & 15;
  int quad = lane >> 4;
  int r = blockIdx.x * 64 + wave * 16 + m;

  s8v afr[4];
  if (r < n) {
    const float* ap = x + (size_t)r * 128 + quad * 8;
#pragma unroll
    for (int kc = 0; kc < 4; kc++) {
      float4 u = *(const float4*)(ap + kc * 32);
      float4 v = *(const float4*)(ap + kc * 32 + 4);
      s8v a;
      a[0] = f2b(u.x); a[1] = f2b(u.y); a[2] = f2b(u.z); a[3] = f2b(u.w);
      a[4] = f2b(v.x); a[5] = f2b(v.y); a[6] = f2b(v.z); a[7] = f2b(v.w);
      afr[kc] = a;
    }
  } else {
#pragma unroll
    for (int kc = 0; kc < 4; kc++) afr[kc] = (s8v)(short)0;
  }

  const short* wp = Wt + (size_t)m * 128 + quad * 8;
  s8v bfr[4][4];
#pragma unroll
  for (int nt = 0; nt < 4; nt++)
#pragma unroll
    for (int kc = 0; kc < 4; kc++)
      bfr[nt][kc] = *(const s8v*)(wp + nt * 16 * 128 + kc * 32);

  f4v acc[4] = {f4v{0,0,0,0}, f4v{0,0,0,0}, f4v{0,0,0,0}, f4v{0,0,0,0}};
#pragma unroll
  for (int kc = 0; kc < 4; kc++)
#pragma unroll
    for (int nt = 0; nt < 4; nt++)
      acc[nt] = __builtin_amdgcn_mfma_f32_16x16x32_bf16(afr[kc], bfr[nt][kc], acc[nt], 0, 0, 0);

  int rbase = blockIdx.x * 64 + wave * 16 + quad * 4;
#pragma unroll
  for (int reg = 0; reg < 4; reg++) {
    int rr = rbase + reg;
    if (rr < n) {
      float dv = dinv[rr];
#pragma unroll
      for (int nt = 0; nt < 4; nt++)
        g1[(size_t)rr * 64 + nt * 16 + m] = __float2bfloat16(acc[nt][reg] * dv);
    }
  }
}

// ---- MFMA gemm2: g2[n,32] = dinv[r]*(z1b[n,64] @ W2[64,32]), bf16 out ----
__global__ __launch_bounds__(256) void k_gemm2(const bf16* __restrict__ z1b,
                                               const short* __restrict__ Wt,  // [32][64] bf16
                                               const float* __restrict__ dinv,
                                               short* __restrict__ g2, int n) {
  int wave = threadIdx.x >> 6;
  int lane = threadIdx.x & 63;
  int m = lane & 15;
  int quad = lane >> 4;
  int r = blockIdx.x * 64 + wave * 16 + m;

  s8v afr[2];
  if (r < n) {
    const short* ap = (const short*)z1b + (size_t)r * 64 + quad * 8;
#pragma unroll
    for (int kc = 0; kc < 2; kc++) afr[kc] = *(const s8v*)(ap + kc * 32);
  } else {
#pragma unroll
    for (int kc = 0; kc < 2; kc++) afr[kc] = (s8v)(short)0;
  }

  const short* wp = Wt + (size_t)m * 64 + quad * 8;
  s8v bfr[2][2];
#pragma unroll
  for (int nt = 0; nt < 2; nt++)
#pragma unroll
    for (int kc = 0; kc < 2; kc++)
      bfr[nt][kc] = *(const s8v*)(wp + nt * 16 * 64 + kc * 32);

  f4v acc[2] = {f4v{0,0,0,0}, f4v{0,0,0,0}};
#pragma unroll
  for (int kc = 0; kc < 2; kc++)
#pragma unroll
    for (int nt = 0; nt < 2; nt++)
      acc[nt] = __builtin_amdgcn_mfma_f32_16x16x32_bf16(afr[kc], bfr[nt][kc], acc[nt], 0, 0, 0);

  int rbase = blockIdx.x * 64 + wave * 16 + quad * 4;
#pragma unroll
  for (int reg = 0; reg < 4; reg++) {
    int rr = rbase + reg;
    if (rr < n) {
      float dv = dinv[rr];
#pragma unroll
      for (int nt = 0; nt < 2; nt++)
        g2[(size_t)rr * 32 + nt * 16 + m] = f2b(acc[nt][reg] * dv);
    }
  }
}

// ---- layer-1 aggregate: 1 wave per 2 dests, dual-row front-loaded pipeline ----
// r14: wave issues BOTH rows' first-window adj (8 loads) then BOTH rows' first-
// window gathers (8 x 16B in flight); row B's fill hides under row A's compute.
// Clamp-addressed loads (no wasted HBM lines), mask-predicated accumulates,
// parallel clamped tails. Per-lane accumulation order identical to r13.
__global__ __launch_bounds__(256) void k_gagg1(const int* __restrict__ row_start,
                                               const int* __restrict__ adj,
                                               const float* __restrict__ dinv,
                                               const short* __restrict__ g,   // g1 bf16 [n][64]
                                               const float* __restrict__ bias,
                                               short* __restrict__ z, int n, int E) {
  int wv = __builtin_amdgcn_readfirstlane((int)threadIdx.x) >> 6;
  int lane = threadIdx.x & 63;
  int grp = lane >> 3;     // 0..7: edge slot
  int fl = lane & 7;       // feature slice: shorts fl*8..fl*8+7 (16 B)
  int c0 = (blockIdx.x * 4 + wv) * 2;
  if (c0 >= n) return;
  int c1 = c0 + 1;
  bool hasB = (c1 < n);
  int sA = row_start[c0];
  int eA = row_start[c1];
  int eB = hasB ? row_start[c1 + 1] : eA;
  int sB = eA;
  const char* gb = (const char*)g;
  int fo = fl * 16;        // byte offset of feature slice within a 128 B row

  // clamped last-valid indices (degree-0 / end-of-array safe)
  int mA = max(min(eA - 1, E - 1), 0);
  int mB = max(min(eB - 1, E - 1), 0);

  // ---- front: both rows' window-0 adj, then both rows' window-0 gathers ----
  int vA0 = adj[min(sA + grp, mA)];
  int vA1 = adj[min(sA + 8 + grp, mA)];
  int vA2 = adj[min(sA + 16 + grp, mA)];
  int vA3 = adj[min(sA + 24 + grp, mA)];
  int vB0 = adj[min(sB + grp, mB)];
  int vB1 = adj[min(sB + 8 + grp, mB)];
  int vB2 = adj[min(sB + 16 + grp, mB)];
  int vB3 = adj[min(sB + 24 + grp, mB)];
  int4 p0 = *(const int4*)(gb + (unsigned)(vA0 + fo));
  int4 p1 = *(const int4*)(gb + (unsigned)(vA1 + fo));
  int4 p2 = *(const int4*)(gb + (unsigned)(vA2 + fo));
  int4 p3 = *(const int4*)(gb + (unsigned)(vA3 + fo));
  int4 q0 = *(const int4*)(gb + (unsigned)(vB0 + fo));
  int4 q1 = *(const int4*)(gb + (unsigned)(vB1 + fo));
  int4 q2 = *(const int4*)(gb + (unsigned)(vB2 + fo));
  int4 q3 = *(const int4*)(gb + (unsigned)(vB3 + fo));

  v2f a0 = {0.f, 0.f}, a1 = {0.f, 0.f}, a2 = {0.f, 0.f}, a3 = {0.f, 0.f};

  // main windows + parallel clamped tail for [j, end)
  auto rest_row = [&](int j, int end) {
    for (; j + 32 <= end; j += 32) {
#pragma unroll
      for (int u = 0; u < 4; u++) {
        int voff = adj[j + u * 8 + grp];
        int4 pk = *(const int4*)(gb + (unsigned)(voff + fo));
        bf2_acc(pk.x, a0); bf2_acc(pk.y, a1); bf2_acc(pk.z, a2); bf2_acc(pk.w, a3);
      }
    }
    if (j < end) {
      int m = end - 1;
      int x0 = adj[min(j + grp, m)];
      int x1 = adj[min(j + 8 + grp, m)];
      int x2 = adj[min(j + 16 + grp, m)];
      int x3 = adj[min(j + 24 + grp, m)];
      int4 t0 = *(const int4*)(gb + (unsigned)(x0 + fo));
      int4 t1 = *(const int4*)(gb + (unsigned)(x1 + fo));
      int4 t2 = *(const int4*)(gb + (unsigned)(x2 + fo));
      int4 t3 = *(const int4*)(gb + (unsigned)(x3 + fo));
      if (j + grp < end)      { bf2_acc(t0.x, a0); bf2_acc(t0.y, a1); bf2_acc(t0.z, a2); bf2_acc(t0.w, a3); }
      if (j + 8 + grp < end)  { bf2_acc(t1.x, a0); bf2_acc(t1.y, a1); bf2_acc(t1.z, a2); bf2_acc(t1.w, a3); }
      if (j + 16 + grp < end) { bf2_acc(t2.x, a0); bf2_acc(t2.y, a1); bf2_acc(t2.z, a2); bf2_acc(t2.w, a3); }
      if (j + 24 + grp < end) { bf2_acc(t3.x, a0); bf2_acc(t3.y, a1); bf2_acc(t3.z, a2); bf2_acc(t3.w, a3); }
    }
  };

  auto finish = [&](int c) {
#pragma unroll
    for (int s = 8; s <= 32; s <<= 1) {
      a0.x += __shfl_xor(a0.x, s); a0.y += __shfl_xor(a0.y, s);
      a1.x += __shfl_xor(a1.x, s); a1.y += __shfl_xor(a1.y, s);
      a2.x += __shfl_xor(a2.x, s); a2.y += __shfl_xor(a2.y, s);
      a3.x += __shfl_xor(a3.x, s); a3.y += __shfl_xor(a3.y, s);
    }
    if (grp == 0) {
      int4 pk = *(const int4*)(gb + (((unsigned)c << 7) + fo));   // self-loop
      bf2_acc(pk.x, a0); bf2_acc(pk.y, a1);
      bf2_acc(pk.z, a2); bf2_acc(pk.w, a3);
      float d = dinv[c];
      float4 b0 = *(const float4*)(bias + fl * 8);
      float4 b1 = *(const float4*)(bias + fl * 8 + 4);
      float v0 = fmaxf(fmaf(d, a0.x, b0.x), 0.f);
      float v1 = fmaxf(fmaf(d, a0.y, b0.y), 0.f);
      float v2 = fmaxf(fmaf(d, a1.x, b0.z), 0.f);
      float v3 = fmaxf(fmaf(d, a1.y, b0.w), 0.f);
      float v4 = fmaxf(fmaf(d, a2.x, b1.x), 0.f);
      float v5 = fmaxf(fmaf(d, a2.y, b1.y), 0.f);
      float v6 = fmaxf(fmaf(d, a3.x, b1.z), 0.f);
      float v7 = fmaxf(fmaf(d, a3.y, b1.w), 0.f);
      int4 out;
      out.x = (int)(unsigned short)f2b(v0) | ((int)f2b(v1) << 16);
      out.y = (int)(unsigned short)f2b(v2) | ((int)f2b(v3) << 16);
      out.z = (int)(unsigned short)f2b(v4) | ((int)f2b(v5) << 16);
      out.w = (int)(unsigned short)f2b(v6) | ((int)f2b(v7) << 16);
      *(int4*)(z + c * 64 + fl * 8) = out;
    }
  };

  // ---- row A: masked window-0 accumulate, then rest ----
  if (sA + grp < eA)      { bf2_acc(p0.x, a0); bf2_acc(p0.y, a1); bf2_acc(p0.z, a2); bf2_acc(p0.w, a3); }
  if (sA + 8 + grp < eA)  { bf2_acc(p1.x, a0); bf2_acc(p1.y, a1); bf2_acc(p1.z, a2); bf2_acc(p1.w, a3); }
  if (sA + 16 + grp < eA) { bf2_acc(p2.x, a0); bf2_acc(p2.y, a1); bf2_acc(p2.z, a2); bf2_acc(p2.w, a3); }
  if (sA + 24 + grp < eA) { bf2_acc(p3.x, a0); bf2_acc(p3.y, a1); bf2_acc(p3.z, a2); bf2_acc(p3.w, a3); }
  rest_row(sA + 32, eA);
  finish(c0);

  // ---- row B (window-0 gathers were in flight during all of row A) ----
  if (hasB) {
    a0 = v2f{0.f, 0.f}; a1 = v2f{0.f, 0.f}; a2 = v2f{0.f, 0.f}; a3 = v2f{0.f, 0.f};
    if (sB + grp < eB)      { bf2_acc(q0.x, a0); bf2_acc(q0.y, a1); bf2_acc(q0.z, a2); bf2_acc(q0.w, a3); }
    if (sB + 8 + grp < eB)  { bf2_acc(q1.x, a0); bf2_acc(q1.y, a1); bf2_acc(q1.z, a2); bf2_acc(q1.w, a3); }
    if (sB + 16 + grp < eB) { bf2_acc(q2.x, a0); bf2_acc(q2.y, a1); bf2_acc(q2.z, a2); bf2_acc(q2.w, a3); }
    if (sB + 24 + grp < eB) { bf2_acc(q3.x, a0); bf2_acc(q3.y, a1); bf2_acc(q3.z, a2); bf2_acc(q3.w, a3); }
    rest_row(sB + 32, eB);
    finish(c1);
  }
}

// ---- layer-2 aggregate: 1 wave per 2 dests, same dual-row pipeline ----
__global__ __launch_bounds__(256) void k_gagg2(const int* __restrict__ row_start,
                                               const int* __restrict__ adj,
                                               const float* __restrict__ dinv,
                                               const short* __restrict__ g,   // g2 bf16 [n][32]
                                               const float* __restrict__ bias,
                                               float* __restrict__ z, int n, int E) {
  int wv = __builtin_amdgcn_readfirstlane((int)threadIdx.x) >> 6;
  int lane = threadIdx.x & 63;
  int grp = lane >> 2;     // 0..15: edge slot
  int fl = lane & 3;       // feature slice: shorts fl*8..fl*8+7 (16 B)
  int c0 = (blockIdx.x * 4 + wv) * 2;
  if (c0 >= n) return;
  int c1 = c0 + 1;
  bool hasB = (c1 < n);
  int sA = row_start[c0];
  int eA = row_start[c1];
  int eB = hasB ? row_start[c1 + 1] : eA;
  int sB = eA;
  const char* gb = (const char*)g;
  int fo = fl * 16;        // byte offset within a 64 B row

  int mA = max(min(eA - 1, E - 1), 0);
  int mB = max(min(eB - 1, E - 1), 0);

  // front: window-0 adj for both rows, then window-0 gathers for both rows
  int vA0 = adj[min(sA + grp, mA)];
  int vA1 = adj[min(sA + 16 + grp, mA)];
  int vB0 = adj[min(sB + grp, mB)];
  int vB1 = adj[min(sB + 16 + grp, mB)];
  int4 p0 = *(const int4*)(gb + (unsigned)((vA0 >> 1) + fo));
  int4 p1 = *(const int4*)(gb + (unsigned)((vA1 >> 1) + fo));
  int4 q0 = *(const int4*)(gb + (unsigned)((vB0 >> 1) + fo));
  int4 q1 = *(const int4*)(gb + (unsigned)((vB1 >> 1) + fo));

  v2f a0 = {0.f, 0.f}, a1 = {0.f, 0.f}, a2 = {0.f, 0.f}, a3 = {0.f, 0.f};

  auto rest_row = [&](int j, int end) {
    for (; j + 32 <= end; j += 32) {
#pragma unroll
      for (int u = 0; u < 2; u++) {
        int voff = adj[j + u * 16 + grp] >> 1;   // r << 6
        int4 pk = *(const int4*)(gb + (unsigned)(voff + fo));
        bf2_acc(pk.x, a0); bf2_acc(pk.y, a1); bf2_acc(pk.z, a2); bf2_acc(pk.w, a3);
      }
    }
    if (j < end) {
      int m = end - 1;
      int x0 = adj[min(j + grp, m)] >> 1;
      int x1 = adj[min(j + 16 + grp, m)] >> 1;
      int4 t0 = *(const int4*)(gb + (unsigned)(x0 + fo));
      int4 t1 = *(const int4*)(gb + (unsigned)(x1 + fo));
      if (j + grp < end)      { bf2_acc(t0.x, a0); bf2_acc(t0.y, a1); bf2_acc(t0.z, a2); bf2_acc(t0.w, a3); }
      if (j + 16 + grp < end) { bf2_acc(t1.x, a0); bf2_acc(t1.y, a1); bf2_acc(t1.z, a2); bf2_acc(t1.w, a3); }
    }
  };

  auto finish = [&](int c) {
#pragma unroll
    for (int s = 4; s <= 32; s <<= 1) {
      a0.x += __shfl_xor(a0.x, s); a0.y += __shfl_xor(a0.y, s);
      a1.x += __shfl_xor(a1.x, s); a1.y += __shfl_xor(a1.y, s);
      a2.x += __shfl_xor(a2.x, s); a2.y += __shfl_xor(a2.y, s);
      a3.x += __shfl_xor(a3.x, s); a3.y += __shfl_xor(a3.y, s);
    }
    if (grp == 0) {
      int4 pk = *(const int4*)(gb + (((unsigned)c << 6) + fo));   // self-loop
      bf2_acc(pk.x, a0); bf2_acc(pk.y, a1);
      bf2_acc(pk.z, a2); bf2_acc(pk.w, a3);
      float d = dinv[c];
      float4 b0 = *(const float4*)(bias + fl * 8);
      float4 b1 = *(const float4*)(bias + fl * 8 + 4);
      float4 o0, o1;
      o0.x = fmaf(d, a0.x, b0.x); o0.y = fmaf(d, a0.y, b0.y);
      o0.z = fmaf(d, a1.x, b0.z); o0.w = fmaf(d, a1.y, b0.w);
      o1.x = fmaf(d, a2.x, b1.x); o1.y = fmaf(d, a2.y, b1.y);
      o1.z = fmaf(d, a3.x, b1.z); o1.w = fmaf(d, a3.y, b1.w);
      *(float4*)(z + c * 32 + fl * 8) = o0;
      *(float4*)(z + c * 32 + fl * 8 + 4) = o1;
    }
  };

  // row A
  if (sA + grp < eA)      { bf2_acc(p0.x, a0); bf2_acc(p0.y, a1); bf2_acc(p0.z, a2); bf2_acc(p0.w, a3); }
  if (sA + 16 + grp < eA) { bf2_acc(p1.x, a0); bf2_acc(p1.y, a1); bf2_acc(p1.z, a2); bf2_acc(p1.w, a3); }
  rest_row(sA + 32, eA);
  finish(c0);

  // row B
  if (hasB) {
    a0 = v2f{0.f, 0.f}; a1 = v2f{0.f, 0.f}; a2 = v2f{0.f, 0.f}; a3 = v2f{0.f, 0.f};
    if (sB + grp < eB)      { bf2_acc(q0.x, a0); bf2_acc(q0.y, a1); bf2_acc(q0.z, a2); bf2_acc(q0.w, a3); }
    if (sB + 16 + grp < eB) { bf2_acc(q1.x, a0); bf2_acc(q1.y, a1); bf2_acc(q1.z, a2); bf2_acc(q1.w, a3); }
    rest_row(sB + 32, eB);
    finish(c1);
  }
}

// ---- link decode: half-wave per label edge, shuffle reduce, fp32 out ----
__global__ __launch_bounds__(256) void k_decode(const int* __restrict__ ea,
                                                const int* __restrict__ eb,
                                                const float* __restrict__ z2,
                                                float* __restrict__ out, int EL) {
  int lane = threadIdx.x & 31;
  int e = blockIdx.x * 8 + (threadIdx.x >> 5);
  if (e >= EL) return;
  int a = ea[e], b = eb[e];
  float p = z2[a * 32 + lane] * z2[b * 32 + lane];
  p += __shfl_down(p, 16);
  p += __shfl_down(p, 8);
  p += __shfl_down(p, 4);
  p += __shfl_down(p, 2);
  p += __shfl_down(p, 1);
  if (lane == 0) out[e] = p;
}

extern "C" void kernel_launch(void* const* d_in, const int* in_sizes, int n_in,
                              void* d_out, int out_size, void* d_ws, size_t ws_size,
                              hipStream_t stream) {
  const float* x   = (const float*)d_in[0];
  const float* W1  = (const float*)d_in[1];
  const float* b1  = (const float*)d_in[2];
  const float* W2  = (const float*)d_in[3];
  const float* b2  = (const float*)d_in[4];
  const int*   ei  = (const int*)d_in[5];   // [2,E]: row=ei[0..E), col=ei[E..2E)
  const int*   eli = (const int*)d_in[6];   // [2,EL]

  const int N  = in_sizes[0] / 128;  // 100000
  const int E  = in_sizes[5] / 2;    // 3200000
  const int EL = in_sizes[6] / 2;    // 200000
  const int* row = ei;
  const int* col = ei + E;
  const int NBUCK = (N + BNODES - 1) / BNODES;   // 391
  const int NCHNK = (E + CHUNK - 1) / CHUNK;     // 782

  // workspace (~60 MB)
  char* ws = (char*)d_ws;
  size_t off = 0;
  auto take = [&](size_t bytes) { char* p = ws + off; off += (bytes + 255) & ~(size_t)255; return p; };
  float* dinv      = (float*)take((size_t)N * 4);
  int*   row_start = (int*)take((size_t)(N + 1) * 4);
  int*   btot      = (int*)take((size_t)NBUCK * 4);
  int*   bbase     = (int*)take((size_t)(NBUCK + 1) * 4);
  short* Wt1       = (short*)take((size_t)64 * 128 * 2);
  short* Wt2       = (short*)take((size_t)32 * 64 * 2);
  int*   chist     = (int*)take((size_t)NCHNK * NBUCK * 4);   // 1.22 MB
  int*   adjTmp    = (int*)take((size_t)E * 4);               // 12.8 MB
  int*   adj       = (int*)take((size_t)E * 4);               // 12.8 MB
  char*  bufH      = take((size_t)N * 64 * 2);                // g1 bf16 / g2 bf16
  short* z1b       = (short*)take((size_t)N * 64 * 2);        // relu'd, bf16
  float* z2        = (float*)take((size_t)N * 32 * 4);
  (void)ws_size; (void)n_in; (void)out_size;

  bf16*  g1 = (bf16*)bufH;
  short* g2 = (short*)bufH;   // aliases g1 (g1 dead when g2 written)

  k_prepW     <<<32, 256, 0, stream>>>(W1, W2, Wt1, Wt2);
  k_hist      <<<NCHNK, 256, 0, stream>>>(col, E, NBUCK, chist);
  k_scanbuck  <<<NBUCK, 256, 0, stream>>>(chist, NCHNK, NBUCK, btot);
  k_scanbase  <<<1, 512, 0, stream>>>(btot, NBUCK, bbase, row_start, N);
  k_binpass   <<<NCHNK, 256, 0, stream>>>(row, col, E, NBUCK, bbase, chist, adjTmp);
  k_bucketsort<<<NBUCK, 256, 0, stream>>>(bbase, adjTmp, adj, row_start, dinv, N);

  k_gemm1<<<(N + 63) / 64, 256, 0, stream>>>(x, Wt1, dinv, g1, N);
  k_gagg1<<<(N + 7) / 8, 256, 0, stream>>>(row_start, adj, dinv, (const short*)g1, b1, z1b, N, E);

  k_gemm2<<<(N + 63) / 64, 256, 0, stream>>>((const bf16*)z1b, Wt2, dinv, g2, N);
  k_gagg2<<<(N + 7) / 8, 256, 0, stream>>>(row_start, adj, dinv, g2, b2, z2, N, E);

  k_decode<<<(EL + 7) / 8, 256, 0, stream>>>(eli, eli + EL, z2, (float*)d_out, EL);
}